// Round 3
// baseline (655.217 us; speedup 1.0000x reference)
//
#include <hip/hip_runtime.h>

// ===========================================================================
// ViewGCNEncoder r18 = r17 with the scatter rebuilt as two-pass binning:
//   pass 1 (in scatter_convert): read edges ONCE coalesced; wave-aggregated
//     append into bins[(xcd, row-partition)] — sequential positions per bin
//     -> full-line writes. Entry packs (row<<16|col, f32 val) in 8B.
//   pass 2 (bin_scatter): partition p handled only by blocks b%8==p (same
//     XCD): reads bins coalesced, scatters into ecv's partition-p region
//     (~800KB, single-L2-resident, single-XCD-owned -> full-line writeback;
//     fill[] atomics XCD-local, no cross-XCD line bouncing).
// r17's lesson (counters): re-scanning the edge stream 8x doubled FETCH
// (30.9->62.8MB) and thrashed L2 so write amplification persisted (85MB).
// Keeps r17's bf16 x->direct GEMM-1 A path + vectorized mask loads.
// 13 launches. Workspace ~99 MB (<=110 MB proven safe).
// ===========================================================================

typedef unsigned short ushort_t;
typedef __attribute__((ext_vector_type(8))) short bf16x8;   // 8 bf16 = 4 VGPRs
typedef __attribute__((ext_vector_type(4))) float f32x4;
typedef __attribute__((ext_vector_type(2))) unsigned int u32x2;
typedef __attribute__((ext_vector_type(4))) unsigned int u32x4;

__device__ __forceinline__ float bf2f(ushort_t u) {
  return __uint_as_float(((unsigned int)u) << 16);
}
__device__ __forceinline__ ushort_t f2bf(float f) {
  unsigned int u = __float_as_uint(f);
  return (ushort_t)((u + 0x7FFFu + ((u >> 16) & 1u)) >> 16);  // RNE
}
__device__ __forceinline__ float read_f(const void* p, int fm, size_t i) {
  return fm ? bf2f(((const ushort_t*)p)[i]) : ((const float*)p)[i];
}

// fragment-order offset: tile-major 16-row tiles; within tile kc-chunk(32 k)
// then lane-linear (lane = (m&15)+16*((k>>3)&3), 8 elems each).
__device__ __forceinline__ size_t frag_off(int m, int k, int K) {
  return (size_t)(m >> 4) * 16 * K + ((size_t)(k >> 5) << 9) +
         (((k >> 3) & 3) << 7) + ((m & 15) << 3) + (k & 7);
}

__device__ __forceinline__ bool mask_keep(const void* mask, int mm, size_t o) {
  switch (mm) {
    case 1:  return ((const int*)mask)[o] != 0;
    case 2:  return ((const unsigned int*)mask)[o] != 0u;
    case 3:  return ((const ushort_t*)mask)[o] != 0;
    default: return ((const unsigned char*)mask)[o] != 0;
  }
}

// ---------------- prep: dtype sniff (blocks 0-2) + zero cnt/fill/binfill ----
__global__ void prep_kernel(const void* __restrict__ x,
                            const void* __restrict__ m1,
                            const void* __restrict__ m2,
                            int* __restrict__ modes,
                            int* __restrict__ zero_region, int zn) {
  if (blockIdx.x == 0) {
    __shared__ int bfok;
    if (threadIdx.x == 0) bfok = 1;
    __syncthreads();
    for (int i = threadIdx.x; i < 8192; i += blockDim.x) {
      ushort_t h = ((const ushort_t*)x)[i];
      int e = (h >> 7) & 0xFF;
      if (!(h == 0 || (e >= 95 && e <= 133))) atomicAnd(&bfok, 0);
    }
    __syncthreads();
    if (threadIdx.x == 0) modes[0] = bfok;   // 1=bf16, 0=f32
  } else if (blockIdx.x <= 2) {
    const void* p = (blockIdx.x == 1) ? m1 : m2;
    __shared__ int ok[4];  // [i32, f32, bf16, u8]
    if (threadIdx.x < 4) ok[threadIdx.x] = 1;
    __syncthreads();
    for (int i = threadIdx.x; i < 4096; i += blockDim.x) {
      unsigned int w = ((const unsigned int*)p)[i];
      if (!(w == 0u || w == 1u)) atomicAnd(&ok[0], 0);
      if (!(w == 0u || w == 0x3F800000u)) atomicAnd(&ok[1], 0);
      unsigned int h16 = w >> 16, l16 = w & 0xFFFFu;
      if (!((h16 == 0u || h16 == 0x3F80u) && (l16 == 0u || l16 == 0x3F80u)))
        atomicAnd(&ok[2], 0);
      if (((w | (w >> 8) | (w >> 16) | (w >> 24)) & 0xFEu) != 0u) atomicAnd(&ok[3], 0);
    }
    __syncthreads();
    if (threadIdx.x == 0)
      modes[blockIdx.x] = ok[0] ? 1 : (ok[1] ? 2 : (ok[2] ? 3 : 0));
  } else {
    int i = (blockIdx.x - 3) * blockDim.x + threadIdx.x;
    int stride = (gridDim.x - 3) * blockDim.x;
    for (; i < zn; i += stride) zero_region[i] = 0;
  }
}

// ---------------- CSR build (frozen) ----------------
__global__ void hist_kernel(const int* __restrict__ rows, int* __restrict__ cnt, int E) {
  int i = blockIdx.x * blockDim.x + threadIdx.x;
  int stride = gridDim.x * blockDim.x;
  for (; i < E; i += stride) atomicAdd(&cnt[rows[i]], 1);
}

__global__ void scan_part_kernel(const int* __restrict__ cnt, int* __restrict__ part, int n) {
  __shared__ int s[256];
  int i = blockIdx.x * 256 + threadIdx.x;
  s[threadIdx.x] = (i < n) ? cnt[i] : 0;
  __syncthreads();
  for (int off = 128; off > 0; off >>= 1) {
    if (threadIdx.x < off) s[threadIdx.x] += s[threadIdx.x + off];
    __syncthreads();
  }
  if (threadIdx.x == 0) part[blockIdx.x] = s[0];
}

__global__ __launch_bounds__(1024) void scan_top_kernel(int* __restrict__ part, int P) {
  __shared__ int s[1024];
  int t = threadIdx.x;
  int v = (t < P) ? part[t] : 0;
  s[t] = v;
  __syncthreads();
  for (int off = 1; off < 1024; off <<= 1) {
    int x = s[t];
    int y = (t >= off) ? s[t - off] : 0;
    __syncthreads();
    s[t] = x + y;
    __syncthreads();
  }
  if (t < P) part[t] = s[t] - v;   // exclusive
}

__global__ void scan_apply_kernel(const int* __restrict__ cnt, const int* __restrict__ part,
                                  int* __restrict__ row_start, int n) {
  __shared__ int s[256];
  int base = part[blockIdx.x];
  int i = blockIdx.x * 256 + threadIdx.x;
  int v = (i < n) ? cnt[i] : 0;
  s[threadIdx.x] = v;
  __syncthreads();
  for (int off = 1; off < 256; off <<= 1) {
    int x = s[threadIdx.x];
    int y = (threadIdx.x >= off) ? s[threadIdx.x - off] : 0;
    __syncthreads();
    s[threadIdx.x] = x + y;
    __syncthreads();
  }
  if (i < n) row_start[i] = base + s[threadIdx.x] - v;
  if (i == n - 1) row_start[n] = base + s[threadIdx.x];
}

// ---------------- pass 1: binning (blocks 0..1023) + convert (1024+) -------
// Bin entry: int2{ (row<<16)|col, f32 val bits } — requires N <= 65535,
// host guarantees via use_bins (else direct-scatter fallback).
// binfill layout: binfill[x*16 + p] (one 64B line per XCD x).
__global__ void scatter_convert_kernel(
    const int* __restrict__ rows, const int* __restrict__ cols,
    const void* __restrict__ vals, const int* __restrict__ fm_p,
    const int* __restrict__ row_start, int* __restrict__ fill,
    int* __restrict__ binfill, int2* __restrict__ bins, int cap, int use_bins,
    int2* __restrict__ ecv, int E,
    const void* __restrict__ W1, const void* __restrict__ W2, const void* __restrict__ W3,
    const void* __restrict__ b1, const void* __restrict__ b2, const void* __restrict__ b3,
    const void* __restrict__ x,
    ushort_t* __restrict__ whi, ushort_t* __restrict__ wlo,
    float* __restrict__ biasf, ushort_t* __restrict__ xbf,
    int n1, int n2, int n3, int h1, int h2, int h3, int K1, int K2, int K3,
    int nx, int Nrows) {
  int fm = *fm_p;
  if (blockIdx.x < 1024) {
    if (use_bins) {
      int xcd = blockIdx.x & 7;
      int lane = threadIdx.x & 63;
      int partsz = (Nrows + 7) >> 3;
      for (int ibase = blockIdx.x * 256; ibase < E; ibase += 1024 * 256) {
        int i = ibase + (int)threadIdx.x;
        bool valid = i < E;
        int r = valid ? rows[i] : 0;
        int c = valid ? cols[i] : 0;
        float v = valid ? read_f(vals, fm, i) : 0.f;
        int p = valid ? (r / partsz) : -1;
#pragma unroll
        for (int pp = 0; pp < 8; ++pp) {
          unsigned long long m = __ballot(p == pp);
          if (!m) continue;
          int cnt_ = (int)__popcll(m);
          int leader = __builtin_ctzll(m);
          int base = 0;
          if (lane == leader) base = atomicAdd(&binfill[xcd * 16 + pp], cnt_);
          base = __shfl(base, leader);
          if (p == pp) {
            int rank = (int)__popcll(m & ((1ull << lane) - 1ull));
            int pos = base + rank;
            if (pos < cap) {
              bins[(size_t)(xcd * 8 + pp) * cap + pos] =
                  make_int2((r << 16) | c, __float_as_int(v));
            } else {  // overflow spill (can't happen for uniform rows)
              int pr = atomicAdd(&fill[r], 1);
              ecv[row_start[r] + pr] = make_int2(c, __float_as_int(v));
            }
          }
        }
      }
    } else {
      // fallback: direct scatter (N > 65535)
      int i = blockIdx.x * blockDim.x + threadIdx.x;
      int stride = 1024 * blockDim.x;
      for (; i < E; i += stride) {
        int r = rows[i];
        int pos = atomicAdd(&fill[r], 1);
        ecv[row_start[r] + pos] = make_int2(cols[i], __float_as_int(read_f(vals, fm, i)));
      }
    }
  } else {
    // --- convert: W split + bias (+ x->bf16 frag only when x is f32) ---
    int wtot = n1 + n2 + n3;
    int btot = h1 + h2 + h3;
    int nx4 = (fm == 1) ? 0 : nx / 4;       // bf16 x: GEMM reads x directly
    int total = wtot + btot + nx4;
    int i = (blockIdx.x - 1024) * blockDim.x + threadIdx.x;
    int stride = (gridDim.x - 1024) * blockDim.x;
    for (; i < total; i += stride) {
      if (i < wtot) {
        const void* src; int j, K; size_t base;
        if (i < n1) { src = W1; j = i; K = K1; base = 0; }
        else if (i < n1 + n2) { src = W2; j = i - n1; K = K2; base = n1; }
        else { src = W3; j = i - n1 - n2; K = K3; base = (size_t)n1 + n2; }
        int n = j / K, k = j - n * K;
        float v = read_f(src, fm, j);
        ushort_t h = f2bf(v);
        size_t o = base + frag_off(n, k, K);
        whi[o] = h;
        wlo[o] = f2bf(v - bf2f(h));
      } else if (i < wtot + btot) {
        int k = i - wtot;
        const void* src; int j;
        if (k < h1) { src = b1; j = k; }
        else if (k < h1 + h2) { src = b2; j = k - h1; }
        else { src = b3; j = k - h1 - h2; }
        biasf[k] = read_f(src, fm, j);
      } else {
        int k4 = i - wtot - btot;          // 4 consecutive elems of x (f32)
        int m = k4 / (K1 / 4);
        int k0 = (k4 - m * (K1 / 4)) * 4;
        f32x4 v = ((const f32x4*)x)[k4];
        ushort_t p0 = f2bf(v[0]), p1 = f2bf(v[1]), p2 = f2bf(v[2]), p3 = f2bf(v[3]);
        size_t o = frag_off(m, k0, K1);
        *(u32x2*)(xbf + o) = (u32x2){
            (unsigned int)p0 | ((unsigned int)p1 << 16),
            (unsigned int)p2 | ((unsigned int)p3 << 16)};
      }
    }
  }
}

// ---------------- pass 2: XCD-local bin -> CSR scatter ----------------------
// Partition p handled by the 128 blocks with blockIdx%8 == p (same XCD as
// pass-1 writes of ecv partition p): fill atomics + ecv stores stay in one
// L2; partition region ~800KB -> lines fill completely before writeback.
__global__ __launch_bounds__(256) void bin_scatter_kernel(
    const int2* __restrict__ bins, const int* __restrict__ binfill,
    const int* __restrict__ row_start, int* __restrict__ fill,
    int2* __restrict__ ecv, int cap) {
  int q = blockIdx.x >> 3, p = blockIdx.x & 7;
#pragma unroll 1
  for (int x = 0; x < 8; ++x) {
    int n = binfill[x * 16 + p];
    if (n > cap) n = cap;
    const int2* bp = bins + (size_t)(x * 8 + p) * cap;
    for (int e = q * 256 + (int)threadIdx.x; e < n; e += 128 * 256) {
      int2 ent = bp[e];
      int r = ((unsigned int)ent.x) >> 16;
      int c = ent.x & 0xFFFF;
      int pos = atomicAdd(&fill[r], 1);
      ecv[row_start[r] + pos] = make_int2(c, ent.y);
    }
  }
}

// ---------------- GEMM: fragment-ordered A and W (frozen r15 core) ----------
template<int KC>
__device__ __forceinline__ void load_afrag(const ushort_t* __restrict__ A,
                                           const ushort_t* __restrict__ Xrow,
                                           bool rowA, int mtile, int K,
                                           int lane, int mr, int quad, int M,
                                           bf16x8* dst) {
  if (rowA) {
    int rr = mtile * 16 + mr;
    if (rr >= M) rr = M - 1;
    const ushort_t* ap = Xrow + (size_t)rr * K + quad * 8;
#pragma unroll
    for (int kc = 0; kc < KC; ++kc) dst[kc] = *(const bf16x8*)(ap + kc * 32);
  } else {
    const ushort_t* ap = A + (size_t)mtile * 16 * K + lane * 8;
#pragma unroll
    for (int kc = 0; kc < KC; ++kc) dst[kc] = *(const bf16x8*)(ap + kc * 512);
  }
}

template<int KC>
__global__ __launch_bounds__(256) void gemm_breg_kernel(
    const ushort_t* __restrict__ A,
    const ushort_t* __restrict__ Xrow, const int* __restrict__ fm_p,
    const ushort_t* __restrict__ Whi, const ushort_t* __restrict__ Wlo,
    const float* __restrict__ bias, ushort_t* __restrict__ g, int ldg,
    int M, int nct) {
  const int K = KC * 32;
  int wave = threadIdx.x >> 6, lane = threadIdx.x & 63;
  int gw = blockIdx.x * 4 + wave;
  int NW = gridDim.x * 4;
  int mr = lane & 15, quad = lane >> 4;
  int ct = gw % nct;
  int nrt = (M + 15) >> 4;
  int ntasks = nct * nrt;
  if (gw >= ntasks) return;

  bool rowA = (Xrow != nullptr) && (*fm_p != 0);

  bf16x8 wh[KC], wl[KC];
  {
    const ushort_t* wp = Whi + (size_t)ct * 16 * K + lane * 8;
    const ushort_t* wq = Wlo + (size_t)ct * 16 * K + lane * 8;
#pragma unroll
    for (int kc = 0; kc < KC; ++kc) {
      wh[kc] = *(const bf16x8*)(wp + kc * 512);
      wl[kc] = *(const bf16x8*)(wq + kc * 512);
    }
  }
  int col = ct * 16 + mr;
  float bv = bias[col];

  int task = gw;
  bf16x8 af[KC];
  load_afrag<KC>(A, Xrow, rowA, task / nct, K, lane, mr, quad, M, af);

#pragma unroll 1
  for (;;) {
    int next = task + NW;
    bool has_next = next < ntasks;
    bf16x8 afn[KC];
    if (has_next)
      load_afrag<KC>(A, Xrow, rowA, next / nct, K, lane, mr, quad, M, afn);

    f32x4 acc[4];
#pragma unroll
    for (int t = 0; t < 4; ++t) acc[t] = (f32x4){0.f, 0.f, 0.f, 0.f};
#pragma unroll
    for (int kc = 0; kc < KC; ++kc) {
      acc[(2 * kc) & 3] = __builtin_amdgcn_mfma_f32_16x16x32_bf16(af[kc], wh[kc], acc[(2 * kc) & 3], 0, 0, 0);
      acc[(2 * kc + 1) & 3] = __builtin_amdgcn_mfma_f32_16x16x32_bf16(af[kc], wl[kc], acc[(2 * kc + 1) & 3], 0, 0, 0);
    }
    int m0 = (task / nct) * 16;
#pragma unroll
    for (int r = 0; r < 4; ++r) {
      int row = m0 + quad * 4 + r;
      float s = ((acc[0][r] + acc[1][r]) + (acc[2][r] + acc[3][r])) + bv;
      if (row < M) g[(size_t)row * ldg + col] = f2bf(s);
    }
    if (!has_next) break;
#pragma unroll
    for (int kc = 0; kc < KC; ++kc) af[kc] = afn[kc];
    task = next;
  }
}

// ---------------- SpMM v8: gathers (r14) + LDS-staged frag flush ------------
template<int MODE, int VEC>
__global__ __launch_bounds__(256) void spmm8_kernel(
    const int* __restrict__ row_start, const int2* __restrict__ ecv,
    const ushort_t* __restrict__ G, int D,
    const void* __restrict__ mask, const int* __restrict__ mmode_p,
    void* __restrict__ outp, int N) {
  __shared__ ushort_t stage[1024];         // 4 rows x up to 256 cols
  int wave = threadIdx.x >> 6, lane = threadIdx.x & 63;
  int r = blockIdx.x * 4 + wave;
  bool active = r < N;
  float a[VEC];
#pragma unroll
  for (int q = 0; q < VEC; ++q) a[q] = 0.f;
  int f0 = lane * VEC;

  if (active) {
    int e  = __builtin_amdgcn_readfirstlane(row_start[r]);
    int e1 = __builtin_amdgcn_readfirstlane(row_start[r + 1]);
    for (; e + 8 <= e1; e += 8) {
      int2 cv[8];
#pragma unroll
      for (int j = 0; j < 8; ++j) cv[j] = ecv[e + j];
      if (VEC == 4) {
        u32x2 gg[8];
#pragma unroll
        for (int j = 0; j < 8; ++j)
          gg[j] = *(const u32x2*)(G + (size_t)cv[j].x * D + f0);
#pragma unroll
        for (int j = 0; j < 8; ++j) {
          float v = __int_as_float(cv[j].y);
          a[0] += v * bf2f((ushort_t)gg[j][0]);
          a[1] += v * bf2f((ushort_t)(gg[j][0] >> 16));
          a[2] += v * bf2f((ushort_t)gg[j][1]);
          a[3] += v * bf2f((ushort_t)(gg[j][1] >> 16));
        }
      } else if (VEC == 2) {
        unsigned int gg[8];
#pragma unroll
        for (int j = 0; j < 8; ++j)
          gg[j] = *(const unsigned int*)(G + (size_t)cv[j].x * D + f0);
#pragma unroll
        for (int j = 0; j < 8; ++j) {
          float v = __int_as_float(cv[j].y);
          a[0] += v * bf2f((ushort_t)gg[j]);
          a[1] += v * bf2f((ushort_t)(gg[j] >> 16));
        }
      } else {
        ushort_t h[8];
#pragma unroll
        for (int j = 0; j < 8; ++j) h[j] = G[(size_t)cv[j].x * D + f0];
#pragma unroll
        for (int j = 0; j < 8; ++j) a[0] += __int_as_float(cv[j].y) * bf2f(h[j]);
      }
    }
    if (e < e1) {
      int idx[8]; float v[8];
#pragma unroll
      for (int j = 0; j < 8; ++j) {
        int ee = e + j;
        bool ok = ee < e1;
        int2 cv = ecv[ok ? ee : e1 - 1];
        idx[j] = cv.x;
        v[j] = ok ? __int_as_float(cv.y) : 0.f;
      }
      if (VEC == 4) {
        u32x2 gg[8];
#pragma unroll
        for (int j = 0; j < 8; ++j)
          gg[j] = *(const u32x2*)(G + (size_t)idx[j] * D + f0);
#pragma unroll
        for (int j = 0; j < 8; ++j) {
          a[0] += v[j] * bf2f((ushort_t)gg[j][0]);
          a[1] += v[j] * bf2f((ushort_t)(gg[j][0] >> 16));
          a[2] += v[j] * bf2f((ushort_t)gg[j][1]);
          a[3] += v[j] * bf2f((ushort_t)(gg[j][1] >> 16));
        }
      } else if (VEC == 2) {
        unsigned int gg[8];
#pragma unroll
        for (int j = 0; j < 8; ++j)
          gg[j] = *(const unsigned int*)(G + (size_t)idx[j] * D + f0);
#pragma unroll
        for (int j = 0; j < 8; ++j) {
          a[0] += v[j] * bf2f((ushort_t)gg[j]);
          a[1] += v[j] * bf2f((ushort_t)(gg[j] >> 16));
        }
      } else {
        ushort_t h[8];
#pragma unroll
        for (int j = 0; j < 8; ++j) h[j] = G[(size_t)idx[j] * D + f0];
#pragma unroll
        for (int j = 0; j < 8; ++j) a[0] += v[j] * bf2f(h[j]);
      }
    }
  }

  if (MODE == 1) {
    if (active) {
      size_t om = (size_t)r * D + f0;      // mask is row-major
      int mm = *mmode_p;
      bool keep[VEC];
      if (mm == 1 || mm == 2) {            // 4B/elem: vector load
        if (VEC == 4) {
          u32x4 mv = *(const u32x4*)((const unsigned int*)mask + om);
#pragma unroll
          for (int q = 0; q < VEC; ++q) keep[q] = mv[q] != 0u;
        } else if (VEC == 2) {
          u32x2 mv = *(const u32x2*)((const unsigned int*)mask + om);
#pragma unroll
          for (int q = 0; q < VEC; ++q) keep[q] = mv[q] != 0u;
        } else {
          keep[0] = ((const unsigned int*)mask)[om] != 0u;
        }
      } else if (mm == 3) {                // bf16: vector load
        if (VEC == 4) {
          u32x2 mv = *(const u32x2*)((const ushort_t*)mask + om);
          keep[0] = (mv[0] & 0xFFFFu) != 0u; keep[1] = (mv[0] >> 16) != 0u;
          keep[2] = (mv[1] & 0xFFFFu) != 0u; keep[3] = (mv[1] >> 16) != 0u;
        } else if (VEC == 2) {
          unsigned int mv = *(const unsigned int*)((const ushort_t*)mask + om);
          keep[0] = (mv & 0xFFFFu) != 0u; keep[1] = (mv >> 16) != 0u;
        } else {
          keep[0] = ((const ushort_t*)mask)[om] != 0;
        }
      } else {                             // u8: vector load
        if (VEC == 4) {
          unsigned int mv = *(const unsigned int*)((const unsigned char*)mask + om);
          keep[0] = (mv & 0xFFu) != 0u;        keep[1] = ((mv >> 8) & 0xFFu) != 0u;
          keep[2] = ((mv >> 16) & 0xFFu) != 0u; keep[3] = (mv >> 24) != 0u;
        } else if (VEC == 2) {
          unsigned int mv = *(const unsigned short*)((const unsigned char*)mask + om);
          keep[0] = (mv & 0xFFu) != 0u; keep[1] = ((mv >> 8) & 0xFFu) != 0u;
        } else {
          keep[0] = ((const unsigned char*)mask)[om] != 0;
        }
      }
#pragma unroll
      for (int q = 0; q < VEC; ++q) {
        float t = a[q];
        t = (t >= 0.f) ? t : 0.2f * t;             // leaky relu 0.2
        t = keep[q] ? t * 1.25f : 0.f;             // keep = 1/(1-0.2)
        stage[wave * D + f0 + q] = f2bf(t);
      }
    }
    __syncthreads();
    // flush: D threads, one 8B (4-elem) piece each; 64B line = 4 rows' chunks
    if (threadIdx.x < D) {
      int g = threadIdx.x >> 3, s = threadIdx.x & 7;   // group, sub
      int kc = g >> 2, quad = g & 3;
      int sr = s >> 1;                                  // source row in block
      int r0 = blockIdx.x * 4;
      if (r0 + sr < N) {
        int kk = kc * 32 + quad * 8 + (s & 1) * 4;
        size_t dst = (size_t)(r0 >> 4) * 16 * D + ((size_t)kc << 9) +
                     (quad << 7) + ((r0 & 15) << 3) + s * 4;
        *(u32x2*)((ushort_t*)outp + dst) = *(const u32x2*)(stage + sr * D + kk);
      }
    }
  } else {
    if (active) {
      size_t o = (size_t)r * D + f0;
#pragma unroll
      for (int q = 0; q < VEC; ++q) ((float*)outp)[o + q] = a[q];
    }
  }
}

// ---------------- launch ----------------
extern "C" void kernel_launch(void* const* d_in, const int* in_sizes, int n_in,
                              void* d_out, int out_size, void* d_ws, size_t ws_size,
                              hipStream_t stream) {
  const void* x     = d_in[0];
  const int*  rows  = (const int*)d_in[1];
  const int*  cols  = (const int*)d_in[2];
  const void* vals  = d_in[3];
  const void* W1    = d_in[4];
  const void* b1    = d_in[5];
  const void* W2    = d_in[6];
  const void* b2    = d_in[7];
  const void* W3    = d_in[8];
  const void* b3    = d_in[9];
  const void* mask1 = d_in[10];
  const void* mask2 = d_in[11];

  const int H1  = in_sizes[5];            // 256
  const int H2  = in_sizes[7];            // 128
  const int OUT = in_sizes[9];            // 64
  const int IN  = in_sizes[4] / H1;       // 256
  const int N   = in_sizes[0] / IN;       // 50000
  const int E   = in_sizes[1];            // 800000
  const int W1n = in_sizes[4], W2n = in_sizes[6], W3n = in_sizes[8];
  const int Np  = ((N + 15) / 16) * 16;
  const int CAP = (E >> 5) + 4096;        // per-bin capacity (avg E/64, 2x+ slack)
  const int use_bins = (N <= 65535) ? 1 : 0;

  char* ws = (char*)d_ws;
  size_t off = 0;
  auto alloc = [&](size_t bytes) -> void* {
    void* p = ws + off;
    off = (off + bytes + 255) & ~(size_t)255;
    return p;
  };
  int*      modes     = (int*)alloc(4 * 4);
  int*      row_start = (int*)alloc((size_t)(N + 1) * 4);
  int*      cnt       = (int*)alloc((size_t)N * 8 + 512);  // [cnt | fill | binfill]
  int*      part      = (int*)alloc(1024 * 4);
  int2*     ecv       = (int2*)alloc((size_t)E * 8);
  int2*     bins      = (int2*)alloc((size_t)64 * CAP * 8);
  ushort_t* whi       = (ushort_t*)alloc((size_t)(W1n + W2n + W3n) * 2);
  ushort_t* wlo       = (ushort_t*)alloc((size_t)(W1n + W2n + W3n) * 2);
  float*    biasf     = (float*)alloc((size_t)(H1 + H2 + OUT) * 4);
  ushort_t* bufA      = (ushort_t*)alloc((size_t)Np * H1 * 2);   // frag
  ushort_t* bufB      = (ushort_t*)alloc((size_t)Np * H1 * 2);   // row-major G
  ushort_t* bufC      = (ushort_t*)alloc((size_t)Np * H1 * 2);   // frag
  // total ~99 MB (<=110 MB proven safe in r3)

  int* fmode   = modes;
  int* mm1     = modes + 1;
  int* mm2     = modes + 2;
  int* fill    = cnt + N;
  int* binfill = cnt + 2 * N;              // 128 ints, zeroed by prep
  ushort_t* w1hi = whi,             *w1lo = wlo;
  ushort_t* w2hi = whi + W1n,       *w2lo = wlo + W1n;
  ushort_t* w3hi = whi + W1n + W2n, *w3lo = wlo + W1n + W2n;

  // prep: sniff (3 blocks) + zero cnt/fill/binfill
  prep_kernel<<<259, 256, 0, stream>>>(x, mask1, mask2, modes, cnt, 2 * N + 128);

  // CSR build with parallel scan
  const int P = (N + 255) / 256;
  hist_kernel<<<1024, 256, 0, stream>>>(rows, cnt, E);
  scan_part_kernel<<<P, 256, 0, stream>>>(cnt, part, N);
  scan_top_kernel<<<1, 1024, 0, stream>>>(part, P);
  scan_apply_kernel<<<P, 256, 0, stream>>>(cnt, part, row_start, N);

  // pass 1: binning (1024 blocks) + conversions (2048 blocks)
  scatter_convert_kernel<<<3072, 256, 0, stream>>>(
      rows, cols, vals, fmode, row_start, fill, binfill, bins, CAP, use_bins,
      ecv, E, W1, W2, W3, b1, b2, b3, x, whi, wlo, biasf, bufA,
      W1n, W2n, W3n, H1, H2, OUT, IN, H1, H2, N * IN, N);
  // pass 2: XCD-local bin -> CSR scatter
  if (use_bins) {
    bin_scatter_kernel<<<1024, 256, 0, stream>>>(
        bins, binfill, row_start, fill, ecv, CAP);
  }

  const int GEMM_BLOCKS = 1024;            // 4096 waves; % {16,8,4} == 0
  int spmm_grid = (N + 3) / 4;

  // layer 1: GEMM(IN->H1, A = x row-major if bf16 else bufA frag)
  //          -> bufB row-major -> SpMM -> bufC frag
  gemm_breg_kernel<8><<<GEMM_BLOCKS, 256, 0, stream>>>(
      bufA, (const ushort_t*)x, fmode, w1hi, w1lo, biasf, bufB, H1, N, H1 / 16);
  spmm8_kernel<1, 4><<<spmm_grid, 256, 0, stream>>>(
      row_start, ecv, bufB, H1, mask1, mm1, bufC, N);
  // layer 2: GEMM(H1->H2, A=bufC frag) -> bufB row-major -> SpMM -> bufA frag
  gemm_breg_kernel<8><<<GEMM_BLOCKS, 256, 0, stream>>>(
      bufC, nullptr, fmode, w2hi, w2lo, biasf + H1, bufB, H2, N, H2 / 16);
  spmm8_kernel<1, 2><<<spmm_grid, 256, 0, stream>>>(
      row_start, ecv, bufB, H2, mask2, mm2, bufA, N);
  // layer 3: GEMM(H2->OUT, A=bufA frag) -> bufB row-major -> SpMM -> f32 d_out
  gemm_breg_kernel<4><<<GEMM_BLOCKS, 256, 0, stream>>>(
      bufA, nullptr, fmode, w3hi, w3lo, biasf + H1 + H2, bufB, OUT, N, OUT / 16);
  spmm8_kernel<0, 1><<<spmm_grid, 256, 0, stream>>>(
      row_start, ecv, bufB, OUT, nullptr, fmode, d_out, N);
}

// Round 4
// 441.710 us; speedup vs baseline: 1.4834x; 1.4834x over previous
//
#include <hip/hip_runtime.h>

// ===========================================================================
// ViewGCNEncoder r19 = r17 + two-pass binning scatter, rebuilt after r18's
// atomic-serialization regression (r18: 100K atomics-with-return on 64
// addresses ~= 12.5K serial round-trips/counter ~= 260us).
//   pass 1: 512 blocks x 1024-edge tiles; LDS hist[8] ranks edges (LDS
//     atomics, per-CU parallel), ONE global atomicAdd per (tile,partition)
//     (~98/counter total). Stores go to gbase[p]+rank: contiguous ~1KB
//     window per tile-partition from one XCD -> full-line writes.
//   pass 2: partition p on blocks b%8==p (same XCD): bins read coalesced,
//     fill[] atomics spread over ~6K rows/partition, ecv partition region
//     (~1MB) single-L2-owned -> full-line writeback.
// Keeps r17: bf16 x -> direct GEMM-1 A path, vectorized mask loads.
// 13 launches. Workspace ~99 MB (<=110 MB proven safe).
// ===========================================================================

typedef unsigned short ushort_t;
typedef __attribute__((ext_vector_type(8))) short bf16x8;   // 8 bf16 = 4 VGPRs
typedef __attribute__((ext_vector_type(4))) float f32x4;
typedef __attribute__((ext_vector_type(2))) unsigned int u32x2;
typedef __attribute__((ext_vector_type(4))) unsigned int u32x4;

__device__ __forceinline__ float bf2f(ushort_t u) {
  return __uint_as_float(((unsigned int)u) << 16);
}
__device__ __forceinline__ ushort_t f2bf(float f) {
  unsigned int u = __float_as_uint(f);
  return (ushort_t)((u + 0x7FFFu + ((u >> 16) & 1u)) >> 16);  // RNE
}
__device__ __forceinline__ float read_f(const void* p, int fm, size_t i) {
  return fm ? bf2f(((const ushort_t*)p)[i]) : ((const float*)p)[i];
}

// fragment-order offset: tile-major 16-row tiles; within tile kc-chunk(32 k)
// then lane-linear (lane = (m&15)+16*((k>>3)&3), 8 elems each).
__device__ __forceinline__ size_t frag_off(int m, int k, int K) {
  return (size_t)(m >> 4) * 16 * K + ((size_t)(k >> 5) << 9) +
         (((k >> 3) & 3) << 7) + ((m & 15) << 3) + (k & 7);
}

__device__ __forceinline__ bool mask_keep(const void* mask, int mm, size_t o) {
  switch (mm) {
    case 1:  return ((const int*)mask)[o] != 0;
    case 2:  return ((const unsigned int*)mask)[o] != 0u;
    case 3:  return ((const ushort_t*)mask)[o] != 0;
    default: return ((const unsigned char*)mask)[o] != 0;
  }
}

// ---------------- prep: dtype sniff (blocks 0-2) + zero cnt/fill/binfill ----
__global__ void prep_kernel(const void* __restrict__ x,
                            const void* __restrict__ m1,
                            const void* __restrict__ m2,
                            int* __restrict__ modes,
                            int* __restrict__ zero_region, int zn) {
  if (blockIdx.x == 0) {
    __shared__ int bfok;
    if (threadIdx.x == 0) bfok = 1;
    __syncthreads();
    for (int i = threadIdx.x; i < 8192; i += blockDim.x) {
      ushort_t h = ((const ushort_t*)x)[i];
      int e = (h >> 7) & 0xFF;
      if (!(h == 0 || (e >= 95 && e <= 133))) atomicAnd(&bfok, 0);
    }
    __syncthreads();
    if (threadIdx.x == 0) modes[0] = bfok;   // 1=bf16, 0=f32
  } else if (blockIdx.x <= 2) {
    const void* p = (blockIdx.x == 1) ? m1 : m2;
    __shared__ int ok[4];  // [i32, f32, bf16, u8]
    if (threadIdx.x < 4) ok[threadIdx.x] = 1;
    __syncthreads();
    for (int i = threadIdx.x; i < 4096; i += blockDim.x) {
      unsigned int w = ((const unsigned int*)p)[i];
      if (!(w == 0u || w == 1u)) atomicAnd(&ok[0], 0);
      if (!(w == 0u || w == 0x3F800000u)) atomicAnd(&ok[1], 0);
      unsigned int h16 = w >> 16, l16 = w & 0xFFFFu;
      if (!((h16 == 0u || h16 == 0x3F80u) && (l16 == 0u || l16 == 0x3F80u)))
        atomicAnd(&ok[2], 0);
      if (((w | (w >> 8) | (w >> 16) | (w >> 24)) & 0xFEu) != 0u) atomicAnd(&ok[3], 0);
    }
    __syncthreads();
    if (threadIdx.x == 0)
      modes[blockIdx.x] = ok[0] ? 1 : (ok[1] ? 2 : (ok[2] ? 3 : 0));
  } else {
    int i = (blockIdx.x - 3) * blockDim.x + threadIdx.x;
    int stride = (gridDim.x - 3) * blockDim.x;
    for (; i < zn; i += stride) zero_region[i] = 0;
  }
}

// ---------------- CSR build (frozen) ----------------
__global__ void hist_kernel(const int* __restrict__ rows, int* __restrict__ cnt, int E) {
  int i = blockIdx.x * blockDim.x + threadIdx.x;
  int stride = gridDim.x * blockDim.x;
  for (; i < E; i += stride) atomicAdd(&cnt[rows[i]], 1);
}

__global__ void scan_part_kernel(const int* __restrict__ cnt, int* __restrict__ part, int n) {
  __shared__ int s[256];
  int i = blockIdx.x * 256 + threadIdx.x;
  s[threadIdx.x] = (i < n) ? cnt[i] : 0;
  __syncthreads();
  for (int off = 128; off > 0; off >>= 1) {
    if (threadIdx.x < off) s[threadIdx.x] += s[threadIdx.x + off];
    __syncthreads();
  }
  if (threadIdx.x == 0) part[blockIdx.x] = s[0];
}

__global__ __launch_bounds__(1024) void scan_top_kernel(int* __restrict__ part, int P) {
  __shared__ int s[1024];
  int t = threadIdx.x;
  int v = (t < P) ? part[t] : 0;
  s[t] = v;
  __syncthreads();
  for (int off = 1; off < 1024; off <<= 1) {
    int x = s[t];
    int y = (t >= off) ? s[t - off] : 0;
    __syncthreads();
    s[t] = x + y;
    __syncthreads();
  }
  if (t < P) part[t] = s[t] - v;   // exclusive
}

__global__ void scan_apply_kernel(const int* __restrict__ cnt, const int* __restrict__ part,
                                  int* __restrict__ row_start, int n) {
  __shared__ int s[256];
  int base = part[blockIdx.x];
  int i = blockIdx.x * 256 + threadIdx.x;
  int v = (i < n) ? cnt[i] : 0;
  s[threadIdx.x] = v;
  __syncthreads();
  for (int off = 1; off < 256; off <<= 1) {
    int x = s[threadIdx.x];
    int y = (threadIdx.x >= off) ? s[threadIdx.x - off] : 0;
    __syncthreads();
    s[threadIdx.x] = x + y;
    __syncthreads();
  }
  if (i < n) row_start[i] = base + s[threadIdx.x] - v;
  if (i == n - 1) row_start[n] = base + s[threadIdx.x];
}

// ---------------- pass 1: tile-binning (blocks 0..511) + convert (512+) ----
// Bin entry: int2{ (row<<16)|col, f32 val bits } — requires N <= 65535
// (use_bins; else direct-scatter fallback). Partition p = row >> 13 (8
// uniform 8192-row partitions). binfill[x*16+p]: one counter line per XCD.
__global__ void scatter_convert_kernel(
    const int* __restrict__ rows, const int* __restrict__ cols,
    const void* __restrict__ vals, const int* __restrict__ fm_p,
    const int* __restrict__ row_start, int* __restrict__ fill,
    int* __restrict__ binfill, int2* __restrict__ bins, int cap, int use_bins,
    int2* __restrict__ ecv, int E,
    const void* __restrict__ W1, const void* __restrict__ W2, const void* __restrict__ W3,
    const void* __restrict__ b1, const void* __restrict__ b2, const void* __restrict__ b3,
    const void* __restrict__ x,
    ushort_t* __restrict__ whi, ushort_t* __restrict__ wlo,
    float* __restrict__ biasf, ushort_t* __restrict__ xbf,
    int n1, int n2, int n3, int h1, int h2, int h3, int K1, int K2, int K3,
    int nx) {
  int fm = *fm_p;
  const int BIN_BLOCKS = 512;
  if (blockIdx.x < BIN_BLOCKS) {
    if (use_bins) {
      __shared__ int hist[8];
      __shared__ int gbase[8];
      int tid = threadIdx.x;
      int xcd = blockIdx.x & 7;
      for (int tb = blockIdx.x; tb * 1024 < E; tb += BIN_BLOCKS) {
        int base = tb * 1024;
        if (tid < 8) hist[tid] = 0;
        __syncthreads();
        int rr[4], cc[4], pp[4], rk[4]; float vv[4];
#pragma unroll
        for (int j = 0; j < 4; ++j) {
          int i = base + j * 256 + tid;
          if (i < E) {
            rr[j] = rows[i]; cc[j] = cols[i]; vv[j] = read_f(vals, fm, i);
            pp[j] = rr[j] >> 13;                   // partition 0..7
            rk[j] = atomicAdd(&hist[pp[j]], 1);    // LDS rank
          } else {
            pp[j] = -1;
          }
        }
        __syncthreads();
        if (tid < 8)
          gbase[tid] = atomicAdd(&binfill[(xcd << 4) + tid], hist[tid]);
        __syncthreads();
#pragma unroll
        for (int j = 0; j < 4; ++j) {
          if (pp[j] >= 0) {
            int pos = gbase[pp[j]] + rk[j];
            if (pos < cap) {
              bins[(size_t)((xcd << 3) + pp[j]) * cap + pos] =
                  make_int2((rr[j] << 16) | cc[j], __float_as_int(vv[j]));
            } else {  // overflow spill (skewed rows only): direct scatter
              int pr = atomicAdd(&fill[rr[j]], 1);
              ecv[row_start[rr[j]] + pr] = make_int2(cc[j], __float_as_int(vv[j]));
            }
          }
        }
      }
    } else {
      // fallback: direct scatter (N > 65535)
      int i = blockIdx.x * blockDim.x + threadIdx.x;
      int stride = BIN_BLOCKS * blockDim.x;
      for (; i < E; i += stride) {
        int r = rows[i];
        int pos = atomicAdd(&fill[r], 1);
        ecv[row_start[r] + pos] = make_int2(cols[i], __float_as_int(read_f(vals, fm, i)));
      }
    }
  } else {
    // --- convert: W split + bias (+ x->bf16 frag only when x is f32) ---
    int wtot = n1 + n2 + n3;
    int btot = h1 + h2 + h3;
    int nx4 = (fm == 1) ? 0 : nx / 4;       // bf16 x: GEMM reads x directly
    int total = wtot + btot + nx4;
    int i = (blockIdx.x - BIN_BLOCKS) * blockDim.x + threadIdx.x;
    int stride = (gridDim.x - BIN_BLOCKS) * blockDim.x;
    for (; i < total; i += stride) {
      if (i < wtot) {
        const void* src; int j, K; size_t base;
        if (i < n1) { src = W1; j = i; K = K1; base = 0; }
        else if (i < n1 + n2) { src = W2; j = i - n1; K = K2; base = n1; }
        else { src = W3; j = i - n1 - n2; K = K3; base = (size_t)n1 + n2; }
        int n = j / K, k = j - n * K;
        float v = read_f(src, fm, j);
        ushort_t h = f2bf(v);
        size_t o = base + frag_off(n, k, K);
        whi[o] = h;
        wlo[o] = f2bf(v - bf2f(h));
      } else if (i < wtot + btot) {
        int k = i - wtot;
        const void* src; int j;
        if (k < h1) { src = b1; j = k; }
        else if (k < h1 + h2) { src = b2; j = k - h1; }
        else { src = b3; j = k - h1 - h2; }
        biasf[k] = read_f(src, fm, j);
      } else {
        int k4 = i - wtot - btot;          // 4 consecutive elems of x (f32)
        int m = k4 / (K1 / 4);
        int k0 = (k4 - m * (K1 / 4)) * 4;
        f32x4 v = ((const f32x4*)x)[k4];
        ushort_t p0 = f2bf(v[0]), p1 = f2bf(v[1]), p2 = f2bf(v[2]), p3 = f2bf(v[3]);
        size_t o = frag_off(m, k0, K1);
        *(u32x2*)(xbf + o) = (u32x2){
            (unsigned int)p0 | ((unsigned int)p1 << 16),
            (unsigned int)p2 | ((unsigned int)p3 << 16)};
      }
    }
  }
}

// ---------------- pass 2: XCD-local bin -> CSR scatter ----------------------
// Partition p handled by the 128 blocks with blockIdx%8 == p: fill atomics
// spread over ~6K rows/partition (XCD-local), ecv partition region ~1MB
// single-L2-owned -> lines fill completely before writeback.
__global__ __launch_bounds__(256) void bin_scatter_kernel(
    const int2* __restrict__ bins, const int* __restrict__ binfill,
    const int* __restrict__ row_start, int* __restrict__ fill,
    int2* __restrict__ ecv, int cap) {
  int p = blockIdx.x & 7, q = blockIdx.x >> 3;
#pragma unroll 1
  for (int x = 0; x < 8; ++x) {
    int n = binfill[x * 16 + p];
    if (n > cap) n = cap;
    const int2* bp = bins + (size_t)((x << 3) + p) * cap;
    for (int e = q * 256 + (int)threadIdx.x; e < n; e += 128 * 256) {
      int2 ent = bp[e];
      int r = ((unsigned int)ent.x) >> 16;
      int c = ent.x & 0xFFFF;
      int pos = atomicAdd(&fill[r], 1);
      ecv[row_start[r] + pos] = make_int2(c, ent.y);
    }
  }
}

// ---------------- GEMM: fragment-ordered A and W (frozen r15 core) ----------
template<int KC>
__device__ __forceinline__ void load_afrag(const ushort_t* __restrict__ A,
                                           const ushort_t* __restrict__ Xrow,
                                           bool rowA, int mtile, int K,
                                           int lane, int mr, int quad, int M,
                                           bf16x8* dst) {
  if (rowA) {
    int rr = mtile * 16 + mr;
    if (rr >= M) rr = M - 1;
    const ushort_t* ap = Xrow + (size_t)rr * K + quad * 8;
#pragma unroll
    for (int kc = 0; kc < KC; ++kc) dst[kc] = *(const bf16x8*)(ap + kc * 32);
  } else {
    const ushort_t* ap = A + (size_t)mtile * 16 * K + lane * 8;
#pragma unroll
    for (int kc = 0; kc < KC; ++kc) dst[kc] = *(const bf16x8*)(ap + kc * 512);
  }
}

template<int KC>
__global__ __launch_bounds__(256) void gemm_breg_kernel(
    const ushort_t* __restrict__ A,
    const ushort_t* __restrict__ Xrow, const int* __restrict__ fm_p,
    const ushort_t* __restrict__ Whi, const ushort_t* __restrict__ Wlo,
    const float* __restrict__ bias, ushort_t* __restrict__ g, int ldg,
    int M, int nct) {
  const int K = KC * 32;
  int wave = threadIdx.x >> 6, lane = threadIdx.x & 63;
  int gw = blockIdx.x * 4 + wave;
  int NW = gridDim.x * 4;
  int mr = lane & 15, quad = lane >> 4;
  int ct = gw % nct;
  int nrt = (M + 15) >> 4;
  int ntasks = nct * nrt;
  if (gw >= ntasks) return;

  bool rowA = (Xrow != nullptr) && (*fm_p != 0);

  bf16x8 wh[KC], wl[KC];
  {
    const ushort_t* wp = Whi + (size_t)ct * 16 * K + lane * 8;
    const ushort_t* wq = Wlo + (size_t)ct * 16 * K + lane * 8;
#pragma unroll
    for (int kc = 0; kc < KC; ++kc) {
      wh[kc] = *(const bf16x8*)(wp + kc * 512);
      wl[kc] = *(const bf16x8*)(wq + kc * 512);
    }
  }
  int col = ct * 16 + mr;
  float bv = bias[col];

  int task = gw;
  bf16x8 af[KC];
  load_afrag<KC>(A, Xrow, rowA, task / nct, K, lane, mr, quad, M, af);

#pragma unroll 1
  for (;;) {
    int next = task + NW;
    bool has_next = next < ntasks;
    bf16x8 afn[KC];
    if (has_next)
      load_afrag<KC>(A, Xrow, rowA, next / nct, K, lane, mr, quad, M, afn);

    f32x4 acc[4];
#pragma unroll
    for (int t = 0; t < 4; ++t) acc[t] = (f32x4){0.f, 0.f, 0.f, 0.f};
#pragma unroll
    for (int kc = 0; kc < KC; ++kc) {
      acc[(2 * kc) & 3] = __builtin_amdgcn_mfma_f32_16x16x32_bf16(af[kc], wh[kc], acc[(2 * kc) & 3], 0, 0, 0);
      acc[(2 * kc + 1) & 3] = __builtin_amdgcn_mfma_f32_16x16x32_bf16(af[kc], wl[kc], acc[(2 * kc + 1) & 3], 0, 0, 0);
    }
    int m0 = (task / nct) * 16;
#pragma unroll
    for (int r = 0; r < 4; ++r) {
      int row = m0 + quad * 4 + r;
      float s = ((acc[0][r] + acc[1][r]) + (acc[2][r] + acc[3][r])) + bv;
      if (row < M) g[(size_t)row * ldg + col] = f2bf(s);
    }
    if (!has_next) break;
#pragma unroll
    for (int kc = 0; kc < KC; ++kc) af[kc] = afn[kc];
    task = next;
  }
}

// ---------------- SpMM v8: gathers (r14) + LDS-staged frag flush ------------
template<int MODE, int VEC>
__global__ __launch_bounds__(256) void spmm8_kernel(
    const int* __restrict__ row_start, const int2* __restrict__ ecv,
    const ushort_t* __restrict__ G, int D,
    const void* __restrict__ mask, const int* __restrict__ mmode_p,
    void* __restrict__ outp, int N) {
  __shared__ ushort_t stage[1024];         // 4 rows x up to 256 cols
  int wave = threadIdx.x >> 6, lane = threadIdx.x & 63;
  int r = blockIdx.x * 4 + wave;
  bool active = r < N;
  float a[VEC];
#pragma unroll
  for (int q = 0; q < VEC; ++q) a[q] = 0.f;
  int f0 = lane * VEC;

  if (active) {
    int e  = __builtin_amdgcn_readfirstlane(row_start[r]);
    int e1 = __builtin_amdgcn_readfirstlane(row_start[r + 1]);
    for (; e + 8 <= e1; e += 8) {
      int2 cv[8];
#pragma unroll
      for (int j = 0; j < 8; ++j) cv[j] = ecv[e + j];
      if (VEC == 4) {
        u32x2 gg[8];
#pragma unroll
        for (int j = 0; j < 8; ++j)
          gg[j] = *(const u32x2*)(G + (size_t)cv[j].x * D + f0);
#pragma unroll
        for (int j = 0; j < 8; ++j) {
          float v = __int_as_float(cv[j].y);
          a[0] += v * bf2f((ushort_t)gg[j][0]);
          a[1] += v * bf2f((ushort_t)(gg[j][0] >> 16));
          a[2] += v * bf2f((ushort_t)gg[j][1]);
          a[3] += v * bf2f((ushort_t)(gg[j][1] >> 16));
        }
      } else if (VEC == 2) {
        unsigned int gg[8];
#pragma unroll
        for (int j = 0; j < 8; ++j)
          gg[j] = *(const unsigned int*)(G + (size_t)cv[j].x * D + f0);
#pragma unroll
        for (int j = 0; j < 8; ++j) {
          float v = __int_as_float(cv[j].y);
          a[0] += v * bf2f((ushort_t)gg[j]);
          a[1] += v * bf2f((ushort_t)(gg[j] >> 16));
        }
      } else {
        ushort_t h[8];
#pragma unroll
        for (int j = 0; j < 8; ++j) h[j] = G[(size_t)cv[j].x * D + f0];
#pragma unroll
        for (int j = 0; j < 8; ++j) a[0] += __int_as_float(cv[j].y) * bf2f(h[j]);
      }
    }
    if (e < e1) {
      int idx[8]; float v[8];
#pragma unroll
      for (int j = 0; j < 8; ++j) {
        int ee = e + j;
        bool ok = ee < e1;
        int2 cv = ecv[ok ? ee : e1 - 1];
        idx[j] = cv.x;
        v[j] = ok ? __int_as_float(cv.y) : 0.f;
      }
      if (VEC == 4) {
        u32x2 gg[8];
#pragma unroll
        for (int j = 0; j < 8; ++j)
          gg[j] = *(const u32x2*)(G + (size_t)idx[j] * D + f0);
#pragma unroll
        for (int j = 0; j < 8; ++j) {
          a[0] += v[j] * bf2f((ushort_t)gg[j][0]);
          a[1] += v[j] * bf2f((ushort_t)(gg[j][0] >> 16));
          a[2] += v[j] * bf2f((ushort_t)gg[j][1]);
          a[3] += v[j] * bf2f((ushort_t)(gg[j][1] >> 16));
        }
      } else if (VEC == 2) {
        unsigned int gg[8];
#pragma unroll
        for (int j = 0; j < 8; ++j)
          gg[j] = *(const unsigned int*)(G + (size_t)idx[j] * D + f0);
#pragma unroll
        for (int j = 0; j < 8; ++j) {
          a[0] += v[j] * bf2f((ushort_t)gg[j]);
          a[1] += v[j] * bf2f((ushort_t)(gg[j] >> 16));
        }
      } else {
        ushort_t h[8];
#pragma unroll
        for (int j = 0; j < 8; ++j) h[j] = G[(size_t)idx[j] * D + f0];
#pragma unroll
        for (int j = 0; j < 8; ++j) a[0] += v[j] * bf2f(h[j]);
      }
    }
  }

  if (MODE == 1) {
    if (active) {
      size_t om = (size_t)r * D + f0;      // mask is row-major
      int mm = *mmode_p;
      bool keep[VEC];
      if (mm == 1 || mm == 2) {            // 4B/elem: vector load
        if (VEC == 4) {
          u32x4 mv = *(const u32x4*)((const unsigned int*)mask + om);
#pragma unroll
          for (int q = 0; q < VEC; ++q) keep[q] = mv[q] != 0u;
        } else if (VEC == 2) {
          u32x2 mv = *(const u32x2*)((const unsigned int*)mask + om);
#pragma unroll
          for (int q = 0; q < VEC; ++q) keep[q] = mv[q] != 0u;
        } else {
          keep[0] = ((const unsigned int*)mask)[om] != 0u;
        }
      } else if (mm == 3) {                // bf16: vector load
        if (VEC == 4) {
          u32x2 mv = *(const u32x2*)((const ushort_t*)mask + om);
          keep[0] = (mv[0] & 0xFFFFu) != 0u; keep[1] = (mv[0] >> 16) != 0u;
          keep[2] = (mv[1] & 0xFFFFu) != 0u; keep[3] = (mv[1] >> 16) != 0u;
        } else if (VEC == 2) {
          unsigned int mv = *(const unsigned int*)((const ushort_t*)mask + om);
          keep[0] = (mv & 0xFFFFu) != 0u; keep[1] = (mv >> 16) != 0u;
        } else {
          keep[0] = ((const ushort_t*)mask)[om] != 0;
        }
      } else {                             // u8: vector load
        if (VEC == 4) {
          unsigned int mv = *(const unsigned int*)((const unsigned char*)mask + om);
          keep[0] = (mv & 0xFFu) != 0u;        keep[1] = ((mv >> 8) & 0xFFu) != 0u;
          keep[2] = ((mv >> 16) & 0xFFu) != 0u; keep[3] = (mv >> 24) != 0u;
        } else if (VEC == 2) {
          unsigned int mv = *(const unsigned short*)((const unsigned char*)mask + om);
          keep[0] = (mv & 0xFFu) != 0u; keep[1] = ((mv >> 8) & 0xFFu) != 0u;
        } else {
          keep[0] = ((const unsigned char*)mask)[om] != 0;
        }
      }
#pragma unroll
      for (int q = 0; q < VEC; ++q) {
        float t = a[q];
        t = (t >= 0.f) ? t : 0.2f * t;             // leaky relu 0.2
        t = keep[q] ? t * 1.25f : 0.f;             // keep = 1/(1-0.2)
        stage[wave * D + f0 + q] = f2bf(t);
      }
    }
    __syncthreads();
    // flush: D threads, one 8B (4-elem) piece each; 64B line = 4 rows' chunks
    if (threadIdx.x < D) {
      int g = threadIdx.x >> 3, s = threadIdx.x & 7;   // group, sub
      int kc = g >> 2, quad = g & 3;
      int sr = s >> 1;                                  // source row in block
      int r0 = blockIdx.x * 4;
      if (r0 + sr < N) {
        int kk = kc * 32 + quad * 8 + (s & 1) * 4;
        size_t dst = (size_t)(r0 >> 4) * 16 * D + ((size_t)kc << 9) +
                     (quad << 7) + ((r0 & 15) << 3) + s * 4;
        *(u32x2*)((ushort_t*)outp + dst) = *(const u32x2*)(stage + sr * D + kk);
      }
    }
  } else {
    if (active) {
      size_t o = (size_t)r * D + f0;
#pragma unroll
      for (int q = 0; q < VEC; ++q) ((float*)outp)[o + q] = a[q];
    }
  }
}

// ---------------- launch ----------------
extern "C" void kernel_launch(void* const* d_in, const int* in_sizes, int n_in,
                              void* d_out, int out_size, void* d_ws, size_t ws_size,
                              hipStream_t stream) {
  const void* x     = d_in[0];
  const int*  rows  = (const int*)d_in[1];
  const int*  cols  = (const int*)d_in[2];
  const void* vals  = d_in[3];
  const void* W1    = d_in[4];
  const void* b1    = d_in[5];
  const void* W2    = d_in[6];
  const void* b2    = d_in[7];
  const void* W3    = d_in[8];
  const void* b3    = d_in[9];
  const void* mask1 = d_in[10];
  const void* mask2 = d_in[11];

  const int H1  = in_sizes[5];            // 256
  const int H2  = in_sizes[7];            // 128
  const int OUT = in_sizes[9];            // 64
  const int IN  = in_sizes[4] / H1;       // 256
  const int N   = in_sizes[0] / IN;       // 50000
  const int E   = in_sizes[1];            // 800000
  const int W1n = in_sizes[4], W2n = in_sizes[6], W3n = in_sizes[8];
  const int Np  = ((N + 15) / 16) * 16;
  const int CAP = (E >> 5) + 2048;        // per-bin cap (avg E/64, 2x+ slack)
  const int use_bins = (N <= 65535) ? 1 : 0;

  char* ws = (char*)d_ws;
  size_t off = 0;
  auto alloc = [&](size_t bytes) -> void* {
    void* p = ws + off;
    off = (off + bytes + 255) & ~(size_t)255;
    return p;
  };
  int*      modes     = (int*)alloc(4 * 4);
  int*      row_start = (int*)alloc((size_t)(N + 1) * 4);
  int*      cnt       = (int*)alloc((size_t)N * 8 + 512);  // [cnt | fill | binfill]
  int*      part      = (int*)alloc(1024 * 4);
  int2*     ecv       = (int2*)alloc((size_t)E * 8);
  int2*     bins      = (int2*)alloc((size_t)64 * CAP * 8);
  ushort_t* whi       = (ushort_t*)alloc((size_t)(W1n + W2n + W3n) * 2);
  ushort_t* wlo       = (ushort_t*)alloc((size_t)(W1n + W2n + W3n) * 2);
  float*    biasf     = (float*)alloc((size_t)(H1 + H2 + OUT) * 4);
  ushort_t* bufA      = (ushort_t*)alloc((size_t)Np * H1 * 2);   // frag
  ushort_t* bufB      = (ushort_t*)alloc((size_t)Np * H1 * 2);   // row-major G
  ushort_t* bufC      = (ushort_t*)alloc((size_t)Np * H1 * 2);   // frag
  // total ~99 MB (<=110 MB proven safe in r3)

  int* fmode   = modes;
  int* mm1     = modes + 1;
  int* mm2     = modes + 2;
  int* fill    = cnt + N;
  int* binfill = cnt + 2 * N;              // 128 ints, zeroed by prep
  ushort_t* w1hi = whi,             *w1lo = wlo;
  ushort_t* w2hi = whi + W1n,       *w2lo = wlo + W1n;
  ushort_t* w3hi = whi + W1n + W2n, *w3lo = wlo + W1n + W2n;

  // prep: sniff (3 blocks) + zero cnt/fill/binfill
  prep_kernel<<<259, 256, 0, stream>>>(x, mask1, mask2, modes, cnt, 2 * N + 128);

  // CSR build with parallel scan
  const int P = (N + 255) / 256;
  hist_kernel<<<1024, 256, 0, stream>>>(rows, cnt, E);
  scan_part_kernel<<<P, 256, 0, stream>>>(cnt, part, N);
  scan_top_kernel<<<1, 1024, 0, stream>>>(part, P);
  scan_apply_kernel<<<P, 256, 0, stream>>>(cnt, part, row_start, N);

  // pass 1: tile-binning (512 blocks) + conversions (2048 blocks)
  scatter_convert_kernel<<<2560, 256, 0, stream>>>(
      rows, cols, vals, fmode, row_start, fill, binfill, bins, CAP, use_bins,
      ecv, E, W1, W2, W3, b1, b2, b3, x, whi, wlo, biasf, bufA,
      W1n, W2n, W3n, H1, H2, OUT, IN, H1, H2, N * IN);
  // pass 2: XCD-local bin -> CSR scatter
  if (use_bins) {
    bin_scatter_kernel<<<1024, 256, 0, stream>>>(
        bins, binfill, row_start, fill, ecv, CAP);
  }

  const int GEMM_BLOCKS = 1024;            // 4096 waves; % {16,8,4} == 0
  int spmm_grid = (N + 3) / 4;

  // layer 1: GEMM(IN->H1, A = x row-major if bf16 else bufA frag)
  //          -> bufB row-major -> SpMM -> bufC frag
  gemm_breg_kernel<8><<<GEMM_BLOCKS, 256, 0, stream>>>(
      bufA, (const ushort_t*)x, fmode, w1hi, w1lo, biasf, bufB, H1, N, H1 / 16);
  spmm8_kernel<1, 4><<<spmm_grid, 256, 0, stream>>>(
      row_start, ecv, bufB, H1, mask1, mm1, bufC, N);
  // layer 2: GEMM(H1->H2, A=bufC frag) -> bufB row-major -> SpMM -> bufA frag
  gemm_breg_kernel<8><<<GEMM_BLOCKS, 256, 0, stream>>>(
      bufC, nullptr, fmode, w2hi, w2lo, biasf + H1, bufB, H2, N, H2 / 16);
  spmm8_kernel<1, 2><<<spmm_grid, 256, 0, stream>>>(
      row_start, ecv, bufB, H2, mask2, mm2, bufA, N);
  // layer 3: GEMM(H2->OUT, A=bufA frag) -> bufB row-major -> SpMM -> f32 d_out
  gemm_breg_kernel<4><<<GEMM_BLOCKS, 256, 0, stream>>>(
      bufA, nullptr, fmode, w3hi, w3lo, biasf + H1 + H2, bufB, OUT, N, OUT / 16);
  spmm8_kernel<0, 1><<<spmm_grid, 256, 0, stream>>>(
      row_start, ecv, bufB, OUT, nullptr, fmode, d_out, N);
}

// Round 5
// 423.915 us; speedup vs baseline: 1.5456x; 1.0420x over previous
//
#include <hip/hip_runtime.h>

// ===========================================================================
// ViewGCNEncoder r20 = r19 with the serial critical path consolidated:
//   (1) hist merged INTO pass-1 binning (edge stream read once; -1 launch),
//       overflow spills to a dedicated ovf list (drained in pass 2) so
//       binning no longer needs row_start.
//   (2) W/bias conversion moved into prep (blocks self-sniff x dtype) so
//       GEMM-1's weights are ready one launch earlier.
//   (3) GEMM-1 fused into the pass-2 launch (block-range split: 1024 scatter
//       blocks + 1024 gemm blocks) -- gemm1 (~12us) hidden under bin scatter.
// r19 lessons kept: LDS-hist tile binning (1 global atomic per tile-part),
// XCD-local pass-2, bf16-x direct GEMM-1 A path, vectorized mask loads.
// 11 launches. Workspace ~105 MB (<=110 MB proven safe).
// ===========================================================================

typedef unsigned short ushort_t;
typedef __attribute__((ext_vector_type(8))) short bf16x8;   // 8 bf16 = 4 VGPRs
typedef __attribute__((ext_vector_type(4))) float f32x4;
typedef __attribute__((ext_vector_type(2))) unsigned int u32x2;
typedef __attribute__((ext_vector_type(4))) unsigned int u32x4;

__device__ __forceinline__ float bf2f(ushort_t u) {
  return __uint_as_float(((unsigned int)u) << 16);
}
__device__ __forceinline__ ushort_t f2bf(float f) {
  unsigned int u = __float_as_uint(f);
  return (ushort_t)((u + 0x7FFFu + ((u >> 16) & 1u)) >> 16);  // RNE
}
__device__ __forceinline__ float read_f(const void* p, int fm, size_t i) {
  return fm ? bf2f(((const ushort_t*)p)[i]) : ((const float*)p)[i];
}

// fragment-order offset: tile-major 16-row tiles; within tile kc-chunk(32 k)
// then lane-linear (lane = (m&15)+16*((k>>3)&3), 8 elems each).
__device__ __forceinline__ size_t frag_off(int m, int k, int K) {
  return (size_t)(m >> 4) * 16 * K + ((size_t)(k >> 5) << 9) +
         (((k >> 3) & 3) << 7) + ((m & 15) << 3) + (k & 7);
}

// ---------------- prep: sniff (0-2) + W/bias convert (3-34) + zero (35+) ---
__global__ void prep_kernel(const void* __restrict__ x,
                            const void* __restrict__ m1,
                            const void* __restrict__ m2,
                            int* __restrict__ modes,
                            int* __restrict__ zero_region, int zn,
                            const void* __restrict__ W1, const void* __restrict__ W2,
                            const void* __restrict__ W3,
                            const void* __restrict__ b1, const void* __restrict__ b2,
                            const void* __restrict__ b3,
                            ushort_t* __restrict__ whi, ushort_t* __restrict__ wlo,
                            float* __restrict__ biasf,
                            int n1, int n2, int n3, int h1, int h2, int h3,
                            int K1, int K2, int K3) {
  if (blockIdx.x == 0) {
    __shared__ int bfok;
    if (threadIdx.x == 0) bfok = 1;
    __syncthreads();
    for (int i = threadIdx.x; i < 8192; i += blockDim.x) {
      ushort_t h = ((const ushort_t*)x)[i];
      int e = (h >> 7) & 0xFF;
      if (!(h == 0 || (e >= 95 && e <= 133))) atomicAnd(&bfok, 0);
    }
    __syncthreads();
    if (threadIdx.x == 0) modes[0] = bfok;   // 1=bf16, 0=f32
  } else if (blockIdx.x <= 2) {
    const void* p = (blockIdx.x == 1) ? m1 : m2;
    __shared__ int ok[4];  // [i32, f32, bf16, u8]
    if (threadIdx.x < 4) ok[threadIdx.x] = 1;
    __syncthreads();
    for (int i = threadIdx.x; i < 4096; i += blockDim.x) {
      unsigned int w = ((const unsigned int*)p)[i];
      if (!(w == 0u || w == 1u)) atomicAnd(&ok[0], 0);
      if (!(w == 0u || w == 0x3F800000u)) atomicAnd(&ok[1], 0);
      unsigned int h16 = w >> 16, l16 = w & 0xFFFFu;
      if (!((h16 == 0u || h16 == 0x3F80u) && (l16 == 0u || l16 == 0x3F80u)))
        atomicAnd(&ok[2], 0);
      if (((w | (w >> 8) | (w >> 16) | (w >> 24)) & 0xFEu) != 0u) atomicAnd(&ok[3], 0);
    }
    __syncthreads();
    if (threadIdx.x == 0)
      modes[blockIdx.x] = ok[0] ? 1 : (ok[1] ? 2 : (ok[2] ? 3 : 0));
  } else if (blockIdx.x < 35) {
    // W split + bias convert; self-sniff x dtype (weights share x's dtype)
    __shared__ int bfok;
    if (threadIdx.x == 0) bfok = 1;
    __syncthreads();
    for (int i = threadIdx.x; i < 8192; i += blockDim.x) {
      ushort_t h = ((const ushort_t*)x)[i];
      int e = (h >> 7) & 0xFF;
      if (!(h == 0 || (e >= 95 && e <= 133))) atomicAnd(&bfok, 0);
    }
    __syncthreads();
    int fm = bfok;
    int wtot = n1 + n2 + n3;
    int total = wtot + h1 + h2 + h3;
    for (int i = (blockIdx.x - 3) * 256 + threadIdx.x; i < total; i += 32 * 256) {
      if (i < wtot) {
        const void* src; int j, K; size_t base;
        if (i < n1) { src = W1; j = i; K = K1; base = 0; }
        else if (i < n1 + n2) { src = W2; j = i - n1; K = K2; base = n1; }
        else { src = W3; j = i - n1 - n2; K = K3; base = (size_t)n1 + n2; }
        int n = j / K, k = j - n * K;
        float v = read_f(src, fm, j);
        ushort_t h = f2bf(v);
        size_t o = base + frag_off(n, k, K);
        whi[o] = h;
        wlo[o] = f2bf(v - bf2f(h));
      } else {
        int k = i - wtot;
        const void* src; int j;
        if (k < h1) { src = b1; j = k; }
        else if (k < h1 + h2) { src = b2; j = k - h1; }
        else { src = b3; j = k - h1 - h2; }
        biasf[k] = read_f(src, fm, j);
      }
    }
  } else {
    int i = (blockIdx.x - 35) * blockDim.x + threadIdx.x;
    int stride = (gridDim.x - 35) * blockDim.x;
    for (; i < zn; i += stride) zero_region[i] = 0;
  }
}

// ---------------- scans (frozen) ----------------
__global__ void scan_part_kernel(const int* __restrict__ cnt, int* __restrict__ part, int n) {
  __shared__ int s[256];
  int i = blockIdx.x * 256 + threadIdx.x;
  s[threadIdx.x] = (i < n) ? cnt[i] : 0;
  __syncthreads();
  for (int off = 128; off > 0; off >>= 1) {
    if (threadIdx.x < off) s[threadIdx.x] += s[threadIdx.x + off];
    __syncthreads();
  }
  if (threadIdx.x == 0) part[blockIdx.x] = s[0];
}

__global__ __launch_bounds__(1024) void scan_top_kernel(int* __restrict__ part, int P) {
  __shared__ int s[1024];
  int t = threadIdx.x;
  int v = (t < P) ? part[t] : 0;
  s[t] = v;
  __syncthreads();
  for (int off = 1; off < 1024; off <<= 1) {
    int x = s[t];
    int y = (t >= off) ? s[t - off] : 0;
    __syncthreads();
    s[t] = x + y;
    __syncthreads();
  }
  if (t < P) part[t] = s[t] - v;   // exclusive
}

__global__ void scan_apply_kernel(const int* __restrict__ cnt, const int* __restrict__ part,
                                  int* __restrict__ row_start, int n) {
  __shared__ int s[256];
  int base = part[blockIdx.x];
  int i = blockIdx.x * 256 + threadIdx.x;
  int v = (i < n) ? cnt[i] : 0;
  s[threadIdx.x] = v;
  __syncthreads();
  for (int off = 1; off < 256; off <<= 1) {
    int x = s[threadIdx.x];
    int y = (threadIdx.x >= off) ? s[threadIdx.x - off] : 0;
    __syncthreads();
    s[threadIdx.x] = x + y;
    __syncthreads();
  }
  if (i < n) row_start[i] = base + s[threadIdx.x] - v;
  if (i == n - 1) row_start[n] = base + s[threadIdx.x];
}

// ---------------- pass 1: hist + tile-binning fused (blocks 0..511) --------
// Reads the edge stream ONCE: per-edge cnt[] atomic (CSR hist, ~16/addr) +
// LDS hist[8] rank + one global reservation per (tile,partition). Overflow
// (extreme skew only) appends to ovf list (counter binfill[128]); blocks
// 512+ do the x->frag convert (f32 input only).
__global__ void hist_bin_kernel(
    const int* __restrict__ rows, const int* __restrict__ cols,
    const void* __restrict__ vals, const int* __restrict__ fm_p,
    int* __restrict__ cnt, int* __restrict__ binfill,
    int2* __restrict__ bins, int cap, int use_bins, int2* __restrict__ ovf,
    int E, const void* __restrict__ x, ushort_t* __restrict__ xbf,
    int K1, int nx) {
  int fm = *fm_p;
  const int BIN_BLOCKS = 512;
  if (blockIdx.x < BIN_BLOCKS) {
    if (use_bins) {
      __shared__ int hist[8];
      __shared__ int gbase[8];
      int tid = threadIdx.x;
      int xcd = blockIdx.x & 7;
      for (int tb = blockIdx.x; tb * 1024 < E; tb += BIN_BLOCKS) {
        int base = tb * 1024;
        if (tid < 8) hist[tid] = 0;
        __syncthreads();
        int rr[4], cc[4], pp[4], rk[4]; float vv[4];
#pragma unroll
        for (int j = 0; j < 4; ++j) {
          int i = base + j * 256 + tid;
          if (i < E) {
            rr[j] = rows[i]; cc[j] = cols[i]; vv[j] = read_f(vals, fm, i);
            atomicAdd(&cnt[rr[j]], 1);             // CSR histogram (fused)
            pp[j] = rr[j] >> 13;                   // partition 0..7
            rk[j] = atomicAdd(&hist[pp[j]], 1);    // LDS rank
          } else {
            pp[j] = -1;
          }
        }
        __syncthreads();
        if (tid < 8)
          gbase[tid] = atomicAdd(&binfill[(xcd << 4) + tid], hist[tid]);
        __syncthreads();
#pragma unroll
        for (int j = 0; j < 4; ++j) {
          if (pp[j] >= 0) {
            int pos = gbase[pp[j]] + rk[j];
            if (pos < cap) {
              bins[(size_t)((xcd << 3) + pp[j]) * cap + pos] =
                  make_int2((rr[j] << 16) | cc[j], __float_as_int(vv[j]));
            } else {  // overflow (skewed rows): append to ovf list
              int op = atomicAdd(&binfill[128], 1);
              ovf[op] = make_int2((rr[j] << 16) | cc[j], __float_as_int(vv[j]));
            }
          }
        }
      }
    } else {
      // fallback (N > 65535): hist only; pass 2 does the direct scatter
      int i = blockIdx.x * blockDim.x + threadIdx.x;
      int stride = BIN_BLOCKS * blockDim.x;
      for (; i < E; i += stride) atomicAdd(&cnt[rows[i]], 1);
    }
  } else {
    // x -> bf16 frag conversion (only when x is f32)
    if (fm == 1) return;
    int nx4 = nx / 4;
    int i = (blockIdx.x - BIN_BLOCKS) * blockDim.x + threadIdx.x;
    int stride = (gridDim.x - BIN_BLOCKS) * blockDim.x;
    for (; i < nx4; i += stride) {
      int m = i / (K1 / 4);
      int k0 = (i - m * (K1 / 4)) * 4;
      f32x4 v = ((const f32x4*)x)[i];
      ushort_t p0 = f2bf(v[0]), p1 = f2bf(v[1]), p2 = f2bf(v[2]), p3 = f2bf(v[3]);
      size_t o = frag_off(m, k0, K1);
      *(u32x2*)(xbf + o) = (u32x2){
          (unsigned int)p0 | ((unsigned int)p1 << 16),
          (unsigned int)p2 | ((unsigned int)p3 << 16)};
    }
  }
}

// ---------------- GEMM body (frozen r15 core, device-callable) --------------
// A-fragment for one lane (mr=lane&15, quad=lane>>4) of kc-chunk kc is the 8
// contiguous row-major elems A[m0+mr][kc*32+quad*8 .. +8] -> when x is bf16
// row-major we load fragments straight from x (rowA path).
template<int KC>
__device__ __forceinline__ void load_afrag(const ushort_t* __restrict__ A,
                                           const ushort_t* __restrict__ Xrow,
                                           bool rowA, int mtile, int K,
                                           int lane, int mr, int quad, int M,
                                           bf16x8* dst) {
  if (rowA) {
    int rr = mtile * 16 + mr;
    if (rr >= M) rr = M - 1;
    const ushort_t* ap = Xrow + (size_t)rr * K + quad * 8;
#pragma unroll
    for (int kc = 0; kc < KC; ++kc) dst[kc] = *(const bf16x8*)(ap + kc * 32);
  } else {
    const ushort_t* ap = A + (size_t)mtile * 16 * K + lane * 8;
#pragma unroll
    for (int kc = 0; kc < KC; ++kc) dst[kc] = *(const bf16x8*)(ap + kc * 512);
  }
}

template<int KC>
__device__ __forceinline__ void gemm_dev(
    int vbid, int nblk, int tid,
    const ushort_t* __restrict__ A, const ushort_t* __restrict__ Xrow, int fm,
    const ushort_t* __restrict__ Whi, const ushort_t* __restrict__ Wlo,
    const float* __restrict__ bias, ushort_t* __restrict__ g, int ldg,
    int M, int nct) {
  const int K = KC * 32;
  int wave = tid >> 6, lane = tid & 63;
  int gw = vbid * 4 + wave;
  int NW = nblk * 4;
  int mr = lane & 15, quad = lane >> 4;
  int ct = gw % nct;
  int nrt = (M + 15) >> 4;
  int ntasks = nct * nrt;
  if (gw >= ntasks) return;

  bool rowA = (Xrow != nullptr) && (fm != 0);

  bf16x8 wh[KC], wl[KC];
  {
    const ushort_t* wp = Whi + (size_t)ct * 16 * K + lane * 8;
    const ushort_t* wq = Wlo + (size_t)ct * 16 * K + lane * 8;
#pragma unroll
    for (int kc = 0; kc < KC; ++kc) {
      wh[kc] = *(const bf16x8*)(wp + kc * 512);
      wl[kc] = *(const bf16x8*)(wq + kc * 512);
    }
  }
  int col = ct * 16 + mr;
  float bv = bias[col];

  int task = gw;
  bf16x8 af[KC];
  load_afrag<KC>(A, Xrow, rowA, task / nct, K, lane, mr, quad, M, af);

#pragma unroll 1
  for (;;) {
    int next = task + NW;
    bool has_next = next < ntasks;
    bf16x8 afn[KC];
    if (has_next)
      load_afrag<KC>(A, Xrow, rowA, next / nct, K, lane, mr, quad, M, afn);

    f32x4 acc[4];
#pragma unroll
    for (int t = 0; t < 4; ++t) acc[t] = (f32x4){0.f, 0.f, 0.f, 0.f};
#pragma unroll
    for (int kc = 0; kc < KC; ++kc) {
      acc[(2 * kc) & 3] = __builtin_amdgcn_mfma_f32_16x16x32_bf16(af[kc], wh[kc], acc[(2 * kc) & 3], 0, 0, 0);
      acc[(2 * kc + 1) & 3] = __builtin_amdgcn_mfma_f32_16x16x32_bf16(af[kc], wl[kc], acc[(2 * kc + 1) & 3], 0, 0, 0);
    }
    int m0 = (task / nct) * 16;
#pragma unroll
    for (int r = 0; r < 4; ++r) {
      int row = m0 + quad * 4 + r;
      float s = ((acc[0][r] + acc[1][r]) + (acc[2][r] + acc[3][r])) + bv;
      if (row < M) g[(size_t)row * ldg + col] = f2bf(s);
    }
    if (!has_next) break;
#pragma unroll
    for (int kc = 0; kc < KC; ++kc) af[kc] = afn[kc];
    task = next;
  }
}

template<int KC>
__global__ __launch_bounds__(256) void gemm_breg_kernel(
    const ushort_t* __restrict__ A,
    const ushort_t* __restrict__ Xrow, const int* __restrict__ fm_p,
    const ushort_t* __restrict__ Whi, const ushort_t* __restrict__ Wlo,
    const float* __restrict__ bias, ushort_t* __restrict__ g, int ldg,
    int M, int nct) {
  gemm_dev<KC>(blockIdx.x, gridDim.x, threadIdx.x, A, Xrow, *fm_p,
               Whi, Wlo, bias, g, ldg, M, nct);
}

// ---------------- pass 2 + GEMM-1 fused -------------------------------------
// Blocks 0..1023: XCD-local bin -> CSR scatter (partition p on b%8==p: fill
// atomics + ecv partition region single-L2-owned) + ovf drain (+ fallback
// direct scatter when !use_bins). Blocks 1024..2047: GEMM-1 (independent:
// reads x/bufA + whi/wlo from prep).
__global__ __launch_bounds__(256) void scatter_gemm_kernel(
    const int2* __restrict__ bins, const int* __restrict__ binfill,
    const int* __restrict__ row_start, int* __restrict__ fill,
    int2* __restrict__ ecv, int cap, const int2* __restrict__ ovf,
    const int* __restrict__ rows, const int* __restrict__ cols,
    const void* __restrict__ vals, const int* __restrict__ fm_p,
    int use_bins, int E,
    const ushort_t* __restrict__ A, const ushort_t* __restrict__ Xrow,
    const ushort_t* __restrict__ Whi, const ushort_t* __restrict__ Wlo,
    const float* __restrict__ bias, ushort_t* __restrict__ g, int ldg,
    int M, int nct) {
  if (blockIdx.x >= 1024) {
    gemm_dev<8>(blockIdx.x - 1024, 1024, threadIdx.x, A, Xrow, *fm_p,
                Whi, Wlo, bias, g, ldg, M, nct);
    return;
  }
  if (use_bins) {
    int p = blockIdx.x & 7, q = blockIdx.x >> 3;
#pragma unroll 1
    for (int x = 0; x < 8; ++x) {
      int n = binfill[x * 16 + p];
      if (n > cap) n = cap;
      const int2* bp = bins + (size_t)((x << 3) + p) * cap;
      for (int e = q * 256 + (int)threadIdx.x; e < n; e += 128 * 256) {
        int2 ent = bp[e];
        int r = ((unsigned int)ent.x) >> 16;
        int c = ent.x & 0xFFFF;
        int pos = atomicAdd(&fill[r], 1);
        ecv[row_start[r] + pos] = make_int2(c, ent.y);
      }
    }
    int ovfn = binfill[128];
    for (int e = blockIdx.x * 256 + (int)threadIdx.x; e < ovfn; e += 1024 * 256) {
      int2 ent = ovf[e];
      int r = ((unsigned int)ent.x) >> 16;
      int c = ent.x & 0xFFFF;
      int pos = atomicAdd(&fill[r], 1);
      ecv[row_start[r] + pos] = make_int2(c, ent.y);
    }
  } else {
    int fm = *fm_p;
    for (int i = blockIdx.x * 256 + (int)threadIdx.x; i < E; i += 1024 * 256) {
      int r = rows[i];
      int pos = atomicAdd(&fill[r], 1);
      ecv[row_start[r] + pos] = make_int2(cols[i], __float_as_int(read_f(vals, fm, i)));
    }
  }
}

// ---------------- SpMM v8: gathers (r14) + LDS-staged frag flush ------------
template<int MODE, int VEC>
__global__ __launch_bounds__(256) void spmm8_kernel(
    const int* __restrict__ row_start, const int2* __restrict__ ecv,
    const ushort_t* __restrict__ G, int D,
    const void* __restrict__ mask, const int* __restrict__ mmode_p,
    void* __restrict__ outp, int N) {
  __shared__ ushort_t stage[1024];         // 4 rows x up to 256 cols
  int wave = threadIdx.x >> 6, lane = threadIdx.x & 63;
  int r = blockIdx.x * 4 + wave;
  bool active = r < N;
  float a[VEC];
#pragma unroll
  for (int q = 0; q < VEC; ++q) a[q] = 0.f;
  int f0 = lane * VEC;

  if (active) {
    int e  = __builtin_amdgcn_readfirstlane(row_start[r]);
    int e1 = __builtin_amdgcn_readfirstlane(row_start[r + 1]);
    for (; e + 8 <= e1; e += 8) {
      int2 cv[8];
#pragma unroll
      for (int j = 0; j < 8; ++j) cv[j] = ecv[e + j];
      if (VEC == 4) {
        u32x2 gg[8];
#pragma unroll
        for (int j = 0; j < 8; ++j)
          gg[j] = *(const u32x2*)(G + (size_t)cv[j].x * D + f0);
#pragma unroll
        for (int j = 0; j < 8; ++j) {
          float v = __int_as_float(cv[j].y);
          a[0] += v * bf2f((ushort_t)gg[j][0]);
          a[1] += v * bf2f((ushort_t)(gg[j][0] >> 16));
          a[2] += v * bf2f((ushort_t)gg[j][1]);
          a[3] += v * bf2f((ushort_t)(gg[j][1] >> 16));
        }
      } else if (VEC == 2) {
        unsigned int gg[8];
#pragma unroll
        for (int j = 0; j < 8; ++j)
          gg[j] = *(const unsigned int*)(G + (size_t)cv[j].x * D + f0);
#pragma unroll
        for (int j = 0; j < 8; ++j) {
          float v = __int_as_float(cv[j].y);
          a[0] += v * bf2f((ushort_t)gg[j]);
          a[1] += v * bf2f((ushort_t)(gg[j] >> 16));
        }
      } else {
        ushort_t h[8];
#pragma unroll
        for (int j = 0; j < 8; ++j) h[j] = G[(size_t)cv[j].x * D + f0];
#pragma unroll
        for (int j = 0; j < 8; ++j) a[0] += __int_as_float(cv[j].y) * bf2f(h[j]);
      }
    }
    if (e < e1) {
      int idx[8]; float v[8];
#pragma unroll
      for (int j = 0; j < 8; ++j) {
        int ee = e + j;
        bool ok = ee < e1;
        int2 cv = ecv[ok ? ee : e1 - 1];
        idx[j] = cv.x;
        v[j] = ok ? __int_as_float(cv.y) : 0.f;
      }
      if (VEC == 4) {
        u32x2 gg[8];
#pragma unroll
        for (int j = 0; j < 8; ++j)
          gg[j] = *(const u32x2*)(G + (size_t)idx[j] * D + f0);
#pragma unroll
        for (int j = 0; j < 8; ++j) {
          a[0] += v[j] * bf2f((ushort_t)gg[j][0]);
          a[1] += v[j] * bf2f((ushort_t)(gg[j][0] >> 16));
          a[2] += v[j] * bf2f((ushort_t)gg[j][1]);
          a[3] += v[j] * bf2f((ushort_t)(gg[j][1] >> 16));
        }
      } else if (VEC == 2) {
        unsigned int gg[8];
#pragma unroll
        for (int j = 0; j < 8; ++j)
          gg[j] = *(const unsigned int*)(G + (size_t)idx[j] * D + f0);
#pragma unroll
        for (int j = 0; j < 8; ++j) {
          a[0] += v[j] * bf2f((ushort_t)gg[j]);
          a[1] += v[j] * bf2f((ushort_t)(gg[j] >> 16));
        }
      } else {
        ushort_t h[8];
#pragma unroll
        for (int j = 0; j < 8; ++j) h[j] = G[(size_t)idx[j] * D + f0];
#pragma unroll
        for (int j = 0; j < 8; ++j) a[0] += v[j] * bf2f(h[j]);
      }
    }
  }

  if (MODE == 1) {
    if (active) {
      size_t om = (size_t)r * D + f0;      // mask is row-major
      int mm = *mmode_p;
      bool keep[VEC];
      if (mm == 1 || mm == 2) {            // 4B/elem: vector load
        if (VEC == 4) {
          u32x4 mv = *(const u32x4*)((const unsigned int*)mask + om);
#pragma unroll
          for (int q = 0; q < VEC; ++q) keep[q] = mv[q] != 0u;
        } else if (VEC == 2) {
          u32x2 mv = *(const u32x2*)((const unsigned int*)mask + om);
#pragma unroll
          for (int q = 0; q < VEC; ++q) keep[q] = mv[q] != 0u;
        } else {
          keep[0] = ((const unsigned int*)mask)[om] != 0u;
        }
      } else if (mm == 3) {                // bf16: vector load
        if (VEC == 4) {
          u32x2 mv = *(const u32x2*)((const ushort_t*)mask + om);
          keep[0] = (mv[0] & 0xFFFFu) != 0u; keep[1] = (mv[0] >> 16) != 0u;
          keep[2] = (mv[1] & 0xFFFFu) != 0u; keep[3] = (mv[1] >> 16) != 0u;
        } else if (VEC == 2) {
          unsigned int mv = *(const unsigned int*)((const ushort_t*)mask + om);
          keep[0] = (mv & 0xFFFFu) != 0u; keep[1] = (mv >> 16) != 0u;
        } else {
          keep[0] = ((const ushort_t*)mask)[om] != 0;
        }
      } else {                             // u8: vector load
        if (VEC == 4) {
          unsigned int mv = *(const unsigned int*)((const unsigned char*)mask + om);
          keep[0] = (mv & 0xFFu) != 0u;        keep[1] = ((mv >> 8) & 0xFFu) != 0u;
          keep[2] = ((mv >> 16) & 0xFFu) != 0u; keep[3] = (mv >> 24) != 0u;
        } else if (VEC == 2) {
          unsigned int mv = *(const unsigned short*)((const unsigned char*)mask + om);
          keep[0] = (mv & 0xFFu) != 0u; keep[1] = ((mv >> 8) & 0xFFu) != 0u;
        } else {
          keep[0] = ((const unsigned char*)mask)[om] != 0;
        }
      }
#pragma unroll
      for (int q = 0; q < VEC; ++q) {
        float t = a[q];
        t = (t >= 0.f) ? t : 0.2f * t;             // leaky relu 0.2
        t = keep[q] ? t * 1.25f : 0.f;             // keep = 1/(1-0.2)
        stage[wave * D + f0 + q] = f2bf(t);
      }
    }
    __syncthreads();
    // flush: D threads, one 8B (4-elem) piece each; 64B line = 4 rows' chunks
    if (threadIdx.x < D) {
      int g = threadIdx.x >> 3, s = threadIdx.x & 7;   // group, sub
      int kc = g >> 2, quad = g & 3;
      int sr = s >> 1;                                  // source row in block
      int r0 = blockIdx.x * 4;
      if (r0 + sr < N) {
        int kk = kc * 32 + quad * 8 + (s & 1) * 4;
        size_t dst = (size_t)(r0 >> 4) * 16 * D + ((size_t)kc << 9) +
                     (quad << 7) + ((r0 & 15) << 3) + s * 4;
        *(u32x2*)((ushort_t*)outp + dst) = *(const u32x2*)(stage + sr * D + kk);
      }
    }
  } else {
    if (active) {
      size_t o = (size_t)r * D + f0;
#pragma unroll
      for (int q = 0; q < VEC; ++q) ((float*)outp)[o + q] = a[q];
    }
  }
}

// ---------------- launch ----------------
extern "C" void kernel_launch(void* const* d_in, const int* in_sizes, int n_in,
                              void* d_out, int out_size, void* d_ws, size_t ws_size,
                              hipStream_t stream) {
  const void* x     = d_in[0];
  const int*  rows  = (const int*)d_in[1];
  const int*  cols  = (const int*)d_in[2];
  const void* vals  = d_in[3];
  const void* W1    = d_in[4];
  const void* b1    = d_in[5];
  const void* W2    = d_in[6];
  const void* b2    = d_in[7];
  const void* W3    = d_in[8];
  const void* b3    = d_in[9];
  const void* mask1 = d_in[10];
  const void* mask2 = d_in[11];

  const int H1  = in_sizes[5];            // 256
  const int H2  = in_sizes[7];            // 128
  const int OUT = in_sizes[9];            // 64
  const int IN  = in_sizes[4] / H1;       // 256
  const int N   = in_sizes[0] / IN;       // 50000
  const int E   = in_sizes[1];            // 800000
  const int W1n = in_sizes[4], W2n = in_sizes[6], W3n = in_sizes[8];
  const int Np  = ((N + 15) / 16) * 16;
  const int CAP = (E >> 5) + 2048;        // per-bin cap (avg E/64, 2x+ slack)
  const int use_bins = (N <= 65535) ? 1 : 0;

  char* ws = (char*)d_ws;
  size_t off = 0;
  auto alloc = [&](size_t bytes) -> void* {
    void* p = ws + off;
    off = (off + bytes + 255) & ~(size_t)255;
    return p;
  };
  int*      modes     = (int*)alloc(4 * 4);
  int*      row_start = (int*)alloc((size_t)(N + 1) * 4);
  int*      cnt       = (int*)alloc((size_t)N * 8 + 768);  // [cnt|fill|binfill+ovfctr]
  int*      part      = (int*)alloc(1024 * 4);
  int2*     ecv       = (int2*)alloc((size_t)E * 8);
  int2*     bins      = (int2*)alloc((size_t)64 * CAP * 8);
  int2*     ovf       = (int2*)alloc((size_t)E * 8);
  ushort_t* whi       = (ushort_t*)alloc((size_t)(W1n + W2n + W3n) * 2);
  ushort_t* wlo       = (ushort_t*)alloc((size_t)(W1n + W2n + W3n) * 2);
  float*    biasf     = (float*)alloc((size_t)(H1 + H2 + OUT) * 4);
  ushort_t* bufA      = (ushort_t*)alloc((size_t)Np * H1 * 2);   // frag
  ushort_t* bufB      = (ushort_t*)alloc((size_t)Np * H1 * 2);   // row-major G
  ushort_t* bufC      = (ushort_t*)alloc((size_t)Np * H1 * 2);   // frag
  // total ~105 MB (<=110 MB proven safe in r3)

  int* fmode   = modes;
  int* mm1     = modes + 1;
  int* mm2     = modes + 2;
  int* fill    = cnt + N;
  int* binfill = cnt + 2 * N;              // 128 bin ctrs + ovf ctr [128]
  ushort_t* w1hi = whi,             *w1lo = wlo;
  ushort_t* w2hi = whi + W1n,       *w2lo = wlo + W1n;
  ushort_t* w3hi = whi + W1n + W2n, *w3lo = wlo + W1n + W2n;

  // 1. prep: sniff + W/bias convert (self-sniff) + zero cnt/fill/binfill/ovfctr
  prep_kernel<<<512, 256, 0, stream>>>(
      x, mask1, mask2, modes, cnt, 2 * N + 132,
      W1, W2, W3, b1, b2, b3, whi, wlo, biasf,
      W1n, W2n, W3n, H1, H2, OUT, IN, H1, H2);

  // 2. hist + binning fused (512 blocks) + x-frag convert f32 (1024 blocks)
  hist_bin_kernel<<<1536, 256, 0, stream>>>(
      rows, cols, vals, fmode, cnt, binfill, bins, CAP, use_bins, ovf,
      E, x, bufA, IN, N * IN);

  // 3-5. CSR scans
  const int P = (N + 255) / 256;
  scan_part_kernel<<<P, 256, 0, stream>>>(cnt, part, N);
  scan_top_kernel<<<1, 1024, 0, stream>>>(part, P);
  scan_apply_kernel<<<P, 256, 0, stream>>>(cnt, part, row_start, N);

  // 6. pass 2 (bin->ecv scatter, 1024 blocks) || GEMM-1 (1024 blocks)
  scatter_gemm_kernel<<<2048, 256, 0, stream>>>(
      bins, binfill, row_start, fill, ecv, CAP, ovf,
      rows, cols, vals, fmode, use_bins, E,
      bufA, (const ushort_t*)x, w1hi, w1lo, biasf, bufB, H1, N, H1 / 16);

  int spmm_grid = (N + 3) / 4;
  const int GEMM_BLOCKS = 1024;

  // 7-11. SpMM/GEMM chain
  spmm8_kernel<1, 4><<<spmm_grid, 256, 0, stream>>>(
      row_start, ecv, bufB, H1, mask1, mm1, bufC, N);
  gemm_breg_kernel<8><<<GEMM_BLOCKS, 256, 0, stream>>>(
      bufC, nullptr, fmode, w2hi, w2lo, biasf + H1, bufB, H2, N, H2 / 16);
  spmm8_kernel<1, 2><<<spmm_grid, 256, 0, stream>>>(
      row_start, ecv, bufB, H2, mask2, mm2, bufA, N);
  gemm_breg_kernel<4><<<GEMM_BLOCKS, 256, 0, stream>>>(
      bufA, nullptr, fmode, w3hi, w3lo, biasf + H1 + H2, bufB, OUT, N, OUT / 16);
  spmm8_kernel<0, 1><<<spmm_grid, 256, 0, stream>>>(
      row_start, ecv, bufB, OUT, nullptr, fmode, d_out, N);
}

// Round 6
// 419.959 us; speedup vs baseline: 1.5602x; 1.0094x over previous
//
#include <hip/hip_runtime.h>

// ===========================================================================
// ViewGCNEncoder r21 = r20 + SpMM MLP deepening (the profile is wall-to-wall
// spmm L1: 68us, 3.4TB/s=54% achievable, VALU 31%, Occ 65% -> latency-bound,
// not BW-bound). Changes confined to spmm8_kernel:
//   (1) 16-edge main chunks (16 independent gathers in flight, was 8) +
//       8-edge clamped tail (avoids redundant requests on short rows).
//   (2) mask load hoisted ABOVE the gather loop (its ~500cy hides under the
//       gathers instead of serializing at the tail).
// Frozen from r20: prep(W-convert), fused hist+bin, scans, pass2+GEMM1 fused,
// GEMM core, bf16-x direct A path. 11 launches. Workspace ~105 MB.
// ===========================================================================

typedef unsigned short ushort_t;
typedef __attribute__((ext_vector_type(8))) short bf16x8;   // 8 bf16 = 4 VGPRs
typedef __attribute__((ext_vector_type(4))) float f32x4;
typedef __attribute__((ext_vector_type(2))) unsigned int u32x2;
typedef __attribute__((ext_vector_type(4))) unsigned int u32x4;

__device__ __forceinline__ float bf2f(ushort_t u) {
  return __uint_as_float(((unsigned int)u) << 16);
}
__device__ __forceinline__ ushort_t f2bf(float f) {
  unsigned int u = __float_as_uint(f);
  return (ushort_t)((u + 0x7FFFu + ((u >> 16) & 1u)) >> 16);  // RNE
}
__device__ __forceinline__ float read_f(const void* p, int fm, size_t i) {
  return fm ? bf2f(((const ushort_t*)p)[i]) : ((const float*)p)[i];
}

// fragment-order offset: tile-major 16-row tiles; within tile kc-chunk(32 k)
// then lane-linear (lane = (m&15)+16*((k>>3)&3), 8 elems each).
__device__ __forceinline__ size_t frag_off(int m, int k, int K) {
  return (size_t)(m >> 4) * 16 * K + ((size_t)(k >> 5) << 9) +
         (((k >> 3) & 3) << 7) + ((m & 15) << 3) + (k & 7);
}

// ---------------- prep: sniff (0-2) + W/bias convert (3-34) + zero (35+) ---
__global__ void prep_kernel(const void* __restrict__ x,
                            const void* __restrict__ m1,
                            const void* __restrict__ m2,
                            int* __restrict__ modes,
                            int* __restrict__ zero_region, int zn,
                            const void* __restrict__ W1, const void* __restrict__ W2,
                            const void* __restrict__ W3,
                            const void* __restrict__ b1, const void* __restrict__ b2,
                            const void* __restrict__ b3,
                            ushort_t* __restrict__ whi, ushort_t* __restrict__ wlo,
                            float* __restrict__ biasf,
                            int n1, int n2, int n3, int h1, int h2, int h3,
                            int K1, int K2, int K3) {
  if (blockIdx.x == 0) {
    __shared__ int bfok;
    if (threadIdx.x == 0) bfok = 1;
    __syncthreads();
    for (int i = threadIdx.x; i < 8192; i += blockDim.x) {
      ushort_t h = ((const ushort_t*)x)[i];
      int e = (h >> 7) & 0xFF;
      if (!(h == 0 || (e >= 95 && e <= 133))) atomicAnd(&bfok, 0);
    }
    __syncthreads();
    if (threadIdx.x == 0) modes[0] = bfok;   // 1=bf16, 0=f32
  } else if (blockIdx.x <= 2) {
    const void* p = (blockIdx.x == 1) ? m1 : m2;
    __shared__ int ok[4];  // [i32, f32, bf16, u8]
    if (threadIdx.x < 4) ok[threadIdx.x] = 1;
    __syncthreads();
    for (int i = threadIdx.x; i < 4096; i += blockDim.x) {
      unsigned int w = ((const unsigned int*)p)[i];
      if (!(w == 0u || w == 1u)) atomicAnd(&ok[0], 0);
      if (!(w == 0u || w == 0x3F800000u)) atomicAnd(&ok[1], 0);
      unsigned int h16 = w >> 16, l16 = w & 0xFFFFu;
      if (!((h16 == 0u || h16 == 0x3F80u) && (l16 == 0u || l16 == 0x3F80u)))
        atomicAnd(&ok[2], 0);
      if (((w | (w >> 8) | (w >> 16) | (w >> 24)) & 0xFEu) != 0u) atomicAnd(&ok[3], 0);
    }
    __syncthreads();
    if (threadIdx.x == 0)
      modes[blockIdx.x] = ok[0] ? 1 : (ok[1] ? 2 : (ok[2] ? 3 : 0));
  } else if (blockIdx.x < 35) {
    // W split + bias convert; self-sniff x dtype (weights share x's dtype)
    __shared__ int bfok;
    if (threadIdx.x == 0) bfok = 1;
    __syncthreads();
    for (int i = threadIdx.x; i < 8192; i += blockDim.x) {
      ushort_t h = ((const ushort_t*)x)[i];
      int e = (h >> 7) & 0xFF;
      if (!(h == 0 || (e >= 95 && e <= 133))) atomicAnd(&bfok, 0);
    }
    __syncthreads();
    int fm = bfok;
    int wtot = n1 + n2 + n3;
    int total = wtot + h1 + h2 + h3;
    for (int i = (blockIdx.x - 3) * 256 + threadIdx.x; i < total; i += 32 * 256) {
      if (i < wtot) {
        const void* src; int j, K; size_t base;
        if (i < n1) { src = W1; j = i; K = K1; base = 0; }
        else if (i < n1 + n2) { src = W2; j = i - n1; K = K2; base = n1; }
        else { src = W3; j = i - n1 - n2; K = K3; base = (size_t)n1 + n2; }
        int n = j / K, k = j - n * K;
        float v = read_f(src, fm, j);
        ushort_t h = f2bf(v);
        size_t o = base + frag_off(n, k, K);
        whi[o] = h;
        wlo[o] = f2bf(v - bf2f(h));
      } else {
        int k = i - wtot;
        const void* src; int j;
        if (k < h1) { src = b1; j = k; }
        else if (k < h1 + h2) { src = b2; j = k - h1; }
        else { src = b3; j = k - h1 - h2; }
        biasf[k] = read_f(src, fm, j);
      }
    }
  } else {
    int i = (blockIdx.x - 35) * blockDim.x + threadIdx.x;
    int stride = (gridDim.x - 35) * blockDim.x;
    for (; i < zn; i += stride) zero_region[i] = 0;
  }
}

// ---------------- scans (frozen) ----------------
__global__ void scan_part_kernel(const int* __restrict__ cnt, int* __restrict__ part, int n) {
  __shared__ int s[256];
  int i = blockIdx.x * 256 + threadIdx.x;
  s[threadIdx.x] = (i < n) ? cnt[i] : 0;
  __syncthreads();
  for (int off = 128; off > 0; off >>= 1) {
    if (threadIdx.x < off) s[threadIdx.x] += s[threadIdx.x + off];
    __syncthreads();
  }
  if (threadIdx.x == 0) part[blockIdx.x] = s[0];
}

__global__ __launch_bounds__(1024) void scan_top_kernel(int* __restrict__ part, int P) {
  __shared__ int s[1024];
  int t = threadIdx.x;
  int v = (t < P) ? part[t] : 0;
  s[t] = v;
  __syncthreads();
  for (int off = 1; off < 1024; off <<= 1) {
    int x = s[t];
    int y = (t >= off) ? s[t - off] : 0;
    __syncthreads();
    s[t] = x + y;
    __syncthreads();
  }
  if (t < P) part[t] = s[t] - v;   // exclusive
}

__global__ void scan_apply_kernel(const int* __restrict__ cnt, const int* __restrict__ part,
                                  int* __restrict__ row_start, int n) {
  __shared__ int s[256];
  int base = part[blockIdx.x];
  int i = blockIdx.x * 256 + threadIdx.x;
  int v = (i < n) ? cnt[i] : 0;
  s[threadIdx.x] = v;
  __syncthreads();
  for (int off = 1; off < 256; off <<= 1) {
    int x = s[threadIdx.x];
    int y = (threadIdx.x >= off) ? s[threadIdx.x - off] : 0;
    __syncthreads();
    s[threadIdx.x] = x + y;
    __syncthreads();
  }
  if (i < n) row_start[i] = base + s[threadIdx.x] - v;
  if (i == n - 1) row_start[n] = base + s[threadIdx.x];
}

// ---------------- pass 1: hist + tile-binning fused (blocks 0..511) --------
__global__ void hist_bin_kernel(
    const int* __restrict__ rows, const int* __restrict__ cols,
    const void* __restrict__ vals, const int* __restrict__ fm_p,
    int* __restrict__ cnt, int* __restrict__ binfill,
    int2* __restrict__ bins, int cap, int use_bins, int2* __restrict__ ovf,
    int E, const void* __restrict__ x, ushort_t* __restrict__ xbf,
    int K1, int nx) {
  int fm = *fm_p;
  const int BIN_BLOCKS = 512;
  if (blockIdx.x < BIN_BLOCKS) {
    if (use_bins) {
      __shared__ int hist[8];
      __shared__ int gbase[8];
      int tid = threadIdx.x;
      int xcd = blockIdx.x & 7;
      for (int tb = blockIdx.x; tb * 1024 < E; tb += BIN_BLOCKS) {
        int base = tb * 1024;
        if (tid < 8) hist[tid] = 0;
        __syncthreads();
        int rr[4], cc[4], pp[4], rk[4]; float vv[4];
#pragma unroll
        for (int j = 0; j < 4; ++j) {
          int i = base + j * 256 + tid;
          if (i < E) {
            rr[j] = rows[i]; cc[j] = cols[i]; vv[j] = read_f(vals, fm, i);
            atomicAdd(&cnt[rr[j]], 1);             // CSR histogram (fused)
            pp[j] = rr[j] >> 13;                   // partition 0..7
            rk[j] = atomicAdd(&hist[pp[j]], 1);    // LDS rank
          } else {
            pp[j] = -1;
          }
        }
        __syncthreads();
        if (tid < 8)
          gbase[tid] = atomicAdd(&binfill[(xcd << 4) + tid], hist[tid]);
        __syncthreads();
#pragma unroll
        for (int j = 0; j < 4; ++j) {
          if (pp[j] >= 0) {
            int pos = gbase[pp[j]] + rk[j];
            if (pos < cap) {
              bins[(size_t)((xcd << 3) + pp[j]) * cap + pos] =
                  make_int2((rr[j] << 16) | cc[j], __float_as_int(vv[j]));
            } else {  // overflow (skewed rows): append to ovf list
              int op = atomicAdd(&binfill[128], 1);
              ovf[op] = make_int2((rr[j] << 16) | cc[j], __float_as_int(vv[j]));
            }
          }
        }
      }
    } else {
      // fallback (N > 65535): hist only; pass 2 does the direct scatter
      int i = blockIdx.x * blockDim.x + threadIdx.x;
      int stride = BIN_BLOCKS * blockDim.x;
      for (; i < E; i += stride) atomicAdd(&cnt[rows[i]], 1);
    }
  } else {
    // x -> bf16 frag conversion (only when x is f32)
    if (fm == 1) return;
    int nx4 = nx / 4;
    int i = (blockIdx.x - BIN_BLOCKS) * blockDim.x + threadIdx.x;
    int stride = (gridDim.x - BIN_BLOCKS) * blockDim.x;
    for (; i < nx4; i += stride) {
      int m = i / (K1 / 4);
      int k0 = (i - m * (K1 / 4)) * 4;
      f32x4 v = ((const f32x4*)x)[i];
      ushort_t p0 = f2bf(v[0]), p1 = f2bf(v[1]), p2 = f2bf(v[2]), p3 = f2bf(v[3]);
      size_t o = frag_off(m, k0, K1);
      *(u32x2*)(xbf + o) = (u32x2){
          (unsigned int)p0 | ((unsigned int)p1 << 16),
          (unsigned int)p2 | ((unsigned int)p3 << 16)};
    }
  }
}

// ---------------- GEMM body (frozen r15 core, device-callable) --------------
template<int KC>
__device__ __forceinline__ void load_afrag(const ushort_t* __restrict__ A,
                                           const ushort_t* __restrict__ Xrow,
                                           bool rowA, int mtile, int K,
                                           int lane, int mr, int quad, int M,
                                           bf16x8* dst) {
  if (rowA) {
    int rr = mtile * 16 + mr;
    if (rr >= M) rr = M - 1;
    const ushort_t* ap = Xrow + (size_t)rr * K + quad * 8;
#pragma unroll
    for (int kc = 0; kc < KC; ++kc) dst[kc] = *(const bf16x8*)(ap + kc * 32);
  } else {
    const ushort_t* ap = A + (size_t)mtile * 16 * K + lane * 8;
#pragma unroll
    for (int kc = 0; kc < KC; ++kc) dst[kc] = *(const bf16x8*)(ap + kc * 512);
  }
}

template<int KC>
__device__ __forceinline__ void gemm_dev(
    int vbid, int nblk, int tid,
    const ushort_t* __restrict__ A, const ushort_t* __restrict__ Xrow, int fm,
    const ushort_t* __restrict__ Whi, const ushort_t* __restrict__ Wlo,
    const float* __restrict__ bias, ushort_t* __restrict__ g, int ldg,
    int M, int nct) {
  const int K = KC * 32;
  int wave = tid >> 6, lane = tid & 63;
  int gw = vbid * 4 + wave;
  int NW = nblk * 4;
  int mr = lane & 15, quad = lane >> 4;
  int ct = gw % nct;
  int nrt = (M + 15) >> 4;
  int ntasks = nct * nrt;
  if (gw >= ntasks) return;

  bool rowA = (Xrow != nullptr) && (fm != 0);

  bf16x8 wh[KC], wl[KC];
  {
    const ushort_t* wp = Whi + (size_t)ct * 16 * K + lane * 8;
    const ushort_t* wq = Wlo + (size_t)ct * 16 * K + lane * 8;
#pragma unroll
    for (int kc = 0; kc < KC; ++kc) {
      wh[kc] = *(const bf16x8*)(wp + kc * 512);
      wl[kc] = *(const bf16x8*)(wq + kc * 512);
    }
  }
  int col = ct * 16 + mr;
  float bv = bias[col];

  int task = gw;
  bf16x8 af[KC];
  load_afrag<KC>(A, Xrow, rowA, task / nct, K, lane, mr, quad, M, af);

#pragma unroll 1
  for (;;) {
    int next = task + NW;
    bool has_next = next < ntasks;
    bf16x8 afn[KC];
    if (has_next)
      load_afrag<KC>(A, Xrow, rowA, next / nct, K, lane, mr, quad, M, afn);

    f32x4 acc[4];
#pragma unroll
    for (int t = 0; t < 4; ++t) acc[t] = (f32x4){0.f, 0.f, 0.f, 0.f};
#pragma unroll
    for (int kc = 0; kc < KC; ++kc) {
      acc[(2 * kc) & 3] = __builtin_amdgcn_mfma_f32_16x16x32_bf16(af[kc], wh[kc], acc[(2 * kc) & 3], 0, 0, 0);
      acc[(2 * kc + 1) & 3] = __builtin_amdgcn_mfma_f32_16x16x32_bf16(af[kc], wl[kc], acc[(2 * kc + 1) & 3], 0, 0, 0);
    }
    int m0 = (task / nct) * 16;
#pragma unroll
    for (int r = 0; r < 4; ++r) {
      int row = m0 + quad * 4 + r;
      float s = ((acc[0][r] + acc[1][r]) + (acc[2][r] + acc[3][r])) + bv;
      if (row < M) g[(size_t)row * ldg + col] = f2bf(s);
    }
    if (!has_next) break;
#pragma unroll
    for (int kc = 0; kc < KC; ++kc) af[kc] = afn[kc];
    task = next;
  }
}

template<int KC>
__global__ __launch_bounds__(256) void gemm_breg_kernel(
    const ushort_t* __restrict__ A,
    const ushort_t* __restrict__ Xrow, const int* __restrict__ fm_p,
    const ushort_t* __restrict__ Whi, const ushort_t* __restrict__ Wlo,
    const float* __restrict__ bias, ushort_t* __restrict__ g, int ldg,
    int M, int nct) {
  gemm_dev<KC>(blockIdx.x, gridDim.x, threadIdx.x, A, Xrow, *fm_p,
               Whi, Wlo, bias, g, ldg, M, nct);
}

// ---------------- pass 2 + GEMM-1 fused -------------------------------------
__global__ __launch_bounds__(256) void scatter_gemm_kernel(
    const int2* __restrict__ bins, const int* __restrict__ binfill,
    const int* __restrict__ row_start, int* __restrict__ fill,
    int2* __restrict__ ecv, int cap, const int2* __restrict__ ovf,
    const int* __restrict__ rows, const int* __restrict__ cols,
    const void* __restrict__ vals, const int* __restrict__ fm_p,
    int use_bins, int E,
    const ushort_t* __restrict__ A, const ushort_t* __restrict__ Xrow,
    const ushort_t* __restrict__ Whi, const ushort_t* __restrict__ Wlo,
    const float* __restrict__ bias, ushort_t* __restrict__ g, int ldg,
    int M, int nct) {
  if (blockIdx.x >= 1024) {
    gemm_dev<8>(blockIdx.x - 1024, 1024, threadIdx.x, A, Xrow, *fm_p,
                Whi, Wlo, bias, g, ldg, M, nct);
    return;
  }
  if (use_bins) {
    int p = blockIdx.x & 7, q = blockIdx.x >> 3;
#pragma unroll 1
    for (int x = 0; x < 8; ++x) {
      int n = binfill[x * 16 + p];
      if (n > cap) n = cap;
      const int2* bp = bins + (size_t)((x << 3) + p) * cap;
      for (int e = q * 256 + (int)threadIdx.x; e < n; e += 128 * 256) {
        int2 ent = bp[e];
        int r = ((unsigned int)ent.x) >> 16;
        int c = ent.x & 0xFFFF;
        int pos = atomicAdd(&fill[r], 1);
        ecv[row_start[r] + pos] = make_int2(c, ent.y);
      }
    }
    int ovfn = binfill[128];
    for (int e = blockIdx.x * 256 + (int)threadIdx.x; e < ovfn; e += 1024 * 256) {
      int2 ent = ovf[e];
      int r = ((unsigned int)ent.x) >> 16;
      int c = ent.x & 0xFFFF;
      int pos = atomicAdd(&fill[r], 1);
      ecv[row_start[r] + pos] = make_int2(c, ent.y);
    }
  } else {
    int fm = *fm_p;
    for (int i = blockIdx.x * 256 + (int)threadIdx.x; i < E; i += 1024 * 256) {
      int r = rows[i];
      int pos = atomicAdd(&fill[r], 1);
      ecv[row_start[r] + pos] = make_int2(cols[i], __float_as_int(read_f(vals, fm, i)));
    }
  }
}

// ---------------- SpMM v9: deep-MLP gathers ---------------------------------
// One wave per row, VEC features/lane. Main loop: 16-edge chunks (16 gathers
// in flight). Tail: 8-edge clamped chunks. Mask loaded BEFORE the gather
// loop so its latency hides under the gathers.
template<int VEC, int CHUNK, bool CLAMP>
__device__ __forceinline__ void spmm_chunk(const int2* __restrict__ ecv,
                                           int base, int e1,
                                           const ushort_t* __restrict__ G,
                                           int D, int f0, float* a) {
  int2 cv[CHUNK];
#pragma unroll
  for (int j = 0; j < CHUNK; ++j) {
    int ee = base + j;
    if (CLAMP) ee = (ee < e1) ? ee : e1 - 1;
    cv[j] = ecv[ee];
  }
  float v[CHUNK];
#pragma unroll
  for (int j = 0; j < CHUNK; ++j) {
    v[j] = __int_as_float(cv[j].y);
    if (CLAMP && (base + j >= e1)) v[j] = 0.f;
  }
  if (VEC == 4) {
    u32x2 gg[CHUNK];
#pragma unroll
    for (int j = 0; j < CHUNK; ++j)
      gg[j] = *(const u32x2*)(G + (size_t)cv[j].x * D + f0);
#pragma unroll
    for (int j = 0; j < CHUNK; ++j) {
      a[0] += v[j] * bf2f((ushort_t)gg[j][0]);
      a[1] += v[j] * bf2f((ushort_t)(gg[j][0] >> 16));
      a[2] += v[j] * bf2f((ushort_t)gg[j][1]);
      a[3] += v[j] * bf2f((ushort_t)(gg[j][1] >> 16));
    }
  } else if (VEC == 2) {
    unsigned int gg[CHUNK];
#pragma unroll
    for (int j = 0; j < CHUNK; ++j)
      gg[j] = *(const unsigned int*)(G + (size_t)cv[j].x * D + f0);
#pragma unroll
    for (int j = 0; j < CHUNK; ++j) {
      a[0] += v[j] * bf2f((ushort_t)gg[j]);
      a[1] += v[j] * bf2f((ushort_t)(gg[j] >> 16));
    }
  } else {
    ushort_t h[CHUNK];
#pragma unroll
    for (int j = 0; j < CHUNK; ++j) h[j] = G[(size_t)cv[j].x * D + f0];
#pragma unroll
    for (int j = 0; j < CHUNK; ++j) a[0] += v[j] * bf2f(h[j]);
  }
}

template<int MODE, int VEC>
__global__ __launch_bounds__(256) void spmm8_kernel(
    const int* __restrict__ row_start, const int2* __restrict__ ecv,
    const ushort_t* __restrict__ G, int D,
    const void* __restrict__ mask, const int* __restrict__ mmode_p,
    void* __restrict__ outp, int N) {
  __shared__ ushort_t stage[1024];         // 4 rows x up to 256 cols
  int wave = threadIdx.x >> 6, lane = threadIdx.x & 63;
  int r = blockIdx.x * 4 + wave;
  bool active = r < N;
  float a[VEC];
#pragma unroll
  for (int q = 0; q < VEC; ++q) a[q] = 0.f;
  int f0 = lane * VEC;

  // ---- hoisted mask load (independent of gather chain) ----
  bool keep[VEC];
#pragma unroll
  for (int q = 0; q < VEC; ++q) keep[q] = true;
  if (MODE == 1 && active) {
    size_t om = (size_t)r * D + f0;        // mask is row-major
    int mm = *mmode_p;
    if (mm == 1 || mm == 2) {              // 4B/elem: vector load
      if (VEC == 4) {
        u32x4 mv = *(const u32x4*)((const unsigned int*)mask + om);
#pragma unroll
        for (int q = 0; q < VEC; ++q) keep[q] = mv[q] != 0u;
      } else if (VEC == 2) {
        u32x2 mv = *(const u32x2*)((const unsigned int*)mask + om);
#pragma unroll
        for (int q = 0; q < VEC; ++q) keep[q] = mv[q] != 0u;
      } else {
        keep[0] = ((const unsigned int*)mask)[om] != 0u;
      }
    } else if (mm == 3) {                  // bf16: vector load
      if (VEC == 4) {
        u32x2 mv = *(const u32x2*)((const ushort_t*)mask + om);
        keep[0] = (mv[0] & 0xFFFFu) != 0u; keep[1] = (mv[0] >> 16) != 0u;
        keep[2] = (mv[1] & 0xFFFFu) != 0u; keep[3] = (mv[1] >> 16) != 0u;
      } else if (VEC == 2) {
        unsigned int mv = *(const unsigned int*)((const ushort_t*)mask + om);
        keep[0] = (mv & 0xFFFFu) != 0u; keep[1] = (mv >> 16) != 0u;
      } else {
        keep[0] = ((const ushort_t*)mask)[om] != 0;
      }
    } else {                               // u8: vector load
      if (VEC == 4) {
        unsigned int mv = *(const unsigned int*)((const unsigned char*)mask + om);
        keep[0] = (mv & 0xFFu) != 0u;         keep[1] = ((mv >> 8) & 0xFFu) != 0u;
        keep[2] = ((mv >> 16) & 0xFFu) != 0u; keep[3] = (mv >> 24) != 0u;
      } else if (VEC == 2) {
        unsigned int mv = *(const unsigned short*)((const unsigned char*)mask + om);
        keep[0] = (mv & 0xFFu) != 0u; keep[1] = ((mv >> 8) & 0xFFu) != 0u;
      } else {
        keep[0] = ((const unsigned char*)mask)[om] != 0;
      }
    }
  }

  if (active) {
    int e  = __builtin_amdgcn_readfirstlane(row_start[r]);
    int e1 = __builtin_amdgcn_readfirstlane(row_start[r + 1]);
    for (; e + 16 <= e1; e += 16)
      spmm_chunk<VEC, 16, false>(ecv, e, e1, G, D, f0, a);
    for (; e < e1; e += 8)
      spmm_chunk<VEC, 8, true>(ecv, e, e1, G, D, f0, a);
  }

  if (MODE == 1) {
    if (active) {
#pragma unroll
      for (int q = 0; q < VEC; ++q) {
        float t = a[q];
        t = (t >= 0.f) ? t : 0.2f * t;             // leaky relu 0.2
        t = keep[q] ? t * 1.25f : 0.f;             // keep = 1/(1-0.2)
        stage[wave * D + f0 + q] = f2bf(t);
      }
    }
    __syncthreads();
    // flush: D threads, one 8B (4-elem) piece each; 64B line = 4 rows' chunks
    if (threadIdx.x < D) {
      int g = threadIdx.x >> 3, s = threadIdx.x & 7;   // group, sub
      int kc = g >> 2, quad = g & 3;
      int sr = s >> 1;                                  // source row in block
      int r0 = blockIdx.x * 4;
      if (r0 + sr < N) {
        int kk = kc * 32 + quad * 8 + (s & 1) * 4;
        size_t dst = (size_t)(r0 >> 4) * 16 * D + ((size_t)kc << 9) +
                     (quad << 7) + ((r0 & 15) << 3) + s * 4;
        *(u32x2*)((ushort_t*)outp + dst) = *(const u32x2*)(stage + sr * D + kk);
      }
    }
  } else {
    if (active) {
      size_t o = (size_t)r * D + f0;
#pragma unroll
      for (int q = 0; q < VEC; ++q) ((float*)outp)[o + q] = a[q];
    }
  }
}

// ---------------- launch ----------------
extern "C" void kernel_launch(void* const* d_in, const int* in_sizes, int n_in,
                              void* d_out, int out_size, void* d_ws, size_t ws_size,
                              hipStream_t stream) {
  const void* x     = d_in[0];
  const int*  rows  = (const int*)d_in[1];
  const int*  cols  = (const int*)d_in[2];
  const void* vals  = d_in[3];
  const void* W1    = d_in[4];
  const void* b1    = d_in[5];
  const void* W2    = d_in[6];
  const void* b2    = d_in[7];
  const void* W3    = d_in[8];
  const void* b3    = d_in[9];
  const void* mask1 = d_in[10];
  const void* mask2 = d_in[11];

  const int H1  = in_sizes[5];            // 256
  const int H2  = in_sizes[7];            // 128
  const int OUT = in_sizes[9];            // 64
  const int IN  = in_sizes[4] / H1;       // 256
  const int N   = in_sizes[0] / IN;       // 50000
  const int E   = in_sizes[1];            // 800000
  const int W1n = in_sizes[4], W2n = in_sizes[6], W3n = in_sizes[8];
  const int Np  = ((N + 15) / 16) * 16;
  const int CAP = (E >> 5) + 2048;        // per-bin cap (avg E/64, 2x+ slack)
  const int use_bins = (N <= 65535) ? 1 : 0;

  char* ws = (char*)d_ws;
  size_t off = 0;
  auto alloc = [&](size_t bytes) -> void* {
    void* p = ws + off;
    off = (off + bytes + 255) & ~(size_t)255;
    return p;
  };
  int*      modes     = (int*)alloc(4 * 4);
  int*      row_start = (int*)alloc((size_t)(N + 1) * 4);
  int*      cnt       = (int*)alloc((size_t)N * 8 + 768);  // [cnt|fill|binfill+ovfctr]
  int*      part      = (int*)alloc(1024 * 4);
  int2*     ecv       = (int2*)alloc((size_t)E * 8);
  int2*     bins      = (int2*)alloc((size_t)64 * CAP * 8);
  int2*     ovf       = (int2*)alloc((size_t)E * 8);
  ushort_t* whi       = (ushort_t*)alloc((size_t)(W1n + W2n + W3n) * 2);
  ushort_t* wlo       = (ushort_t*)alloc((size_t)(W1n + W2n + W3n) * 2);
  float*    biasf     = (float*)alloc((size_t)(H1 + H2 + OUT) * 4);
  ushort_t* bufA      = (ushort_t*)alloc((size_t)Np * H1 * 2);   // frag
  ushort_t* bufB      = (ushort_t*)alloc((size_t)Np * H1 * 2);   // row-major G
  ushort_t* bufC      = (ushort_t*)alloc((size_t)Np * H1 * 2);   // frag
  // total ~105 MB (<=110 MB proven safe in r3)

  int* fmode   = modes;
  int* mm1     = modes + 1;
  int* mm2     = modes + 2;
  int* fill    = cnt + N;
  int* binfill = cnt + 2 * N;              // 128 bin ctrs + ovf ctr [128]
  ushort_t* w1hi = whi,             *w1lo = wlo;
  ushort_t* w2hi = whi + W1n,       *w2lo = wlo + W1n;
  ushort_t* w3hi = whi + W1n + W2n, *w3lo = wlo + W1n + W2n;

  // 1. prep: sniff + W/bias convert (self-sniff) + zero cnt/fill/binfill/ovfctr
  prep_kernel<<<512, 256, 0, stream>>>(
      x, mask1, mask2, modes, cnt, 2 * N + 132,
      W1, W2, W3, b1, b2, b3, whi, wlo, biasf,
      W1n, W2n, W3n, H1, H2, OUT, IN, H1, H2);

  // 2. hist + binning fused (512 blocks) + x-frag convert f32 (1024 blocks)
  hist_bin_kernel<<<1536, 256, 0, stream>>>(
      rows, cols, vals, fmode, cnt, binfill, bins, CAP, use_bins, ovf,
      E, x, bufA, IN, N * IN);

  // 3-5. CSR scans
  const int P = (N + 255) / 256;
  scan_part_kernel<<<P, 256, 0, stream>>>(cnt, part, N);
  scan_top_kernel<<<1, 1024, 0, stream>>>(part, P);
  scan_apply_kernel<<<P, 256, 0, stream>>>(cnt, part, row_start, N);

  // 6. pass 2 (bin->ecv scatter, 1024 blocks) || GEMM-1 (1024 blocks)
  scatter_gemm_kernel<<<2048, 256, 0, stream>>>(
      bins, binfill, row_start, fill, ecv, CAP, ovf,
      rows, cols, vals, fmode, use_bins, E,
      bufA, (const ushort_t*)x, w1hi, w1lo, biasf, bufB, H1, N, H1 / 16);

  int spmm_grid = (N + 3) / 4;
  const int GEMM_BLOCKS = 1024;

  // 7-11. SpMM/GEMM chain
  spmm8_kernel<1, 4><<<spmm_grid, 256, 0, stream>>>(
      row_start, ecv, bufB, H1, mask1, mm1, bufC, N);
  gemm_breg_kernel<8><<<GEMM_BLOCKS, 256, 0, stream>>>(
      bufC, nullptr, fmode, w2hi, w2lo, biasf + H1, bufB, H2, N, H2 / 16);
  spmm8_kernel<1, 2><<<spmm_grid, 256, 0, stream>>>(
      row_start, ecv, bufB, H2, mask2, mm2, bufA, N);
  gemm_breg_kernel<4><<<GEMM_BLOCKS, 256, 0, stream>>>(
      bufA, nullptr, fmode, w3hi, w3lo, biasf + H1 + H2, bufB, OUT, N, OUT / 16);
  spmm8_kernel<0, 1><<<spmm_grid, 256, 0, stream>>>(
      row_start, ecv, bufB, OUT, nullptr, fmode, d_out, N);
}

// Round 7
// 417.986 us; speedup vs baseline: 1.5676x; 1.0047x over previous
//
#include <hip/hip_runtime.h>

// ===========================================================================
// ViewGCNEncoder r22 = r21 + XCD-sharded CSR histogram.
// r21 lesson (counters): spmm1 FETCH=208MB == 8 XCD x G(25.6MB) compulsory
// floor; 16-deep MLP null -> spmm is beyond-L2-traffic-bound at its floor.
// FROZEN. This round: hist_bin's 800K atomicAdd over 50K counters bounce
// 64B lines across all 8 XCDs (~256 RMW/line interleaved). Shard: cnt8[8][N],
// block b atomics only shard b&7 (XCD-local RMW); scan_part sums shards.
// 11 launches. Workspace ~107 MB (<=110 MB proven safe).
// ===========================================================================

typedef unsigned short ushort_t;
typedef __attribute__((ext_vector_type(8))) short bf16x8;   // 8 bf16 = 4 VGPRs
typedef __attribute__((ext_vector_type(4))) float f32x4;
typedef __attribute__((ext_vector_type(2))) unsigned int u32x2;
typedef __attribute__((ext_vector_type(4))) unsigned int u32x4;

__device__ __forceinline__ float bf2f(ushort_t u) {
  return __uint_as_float(((unsigned int)u) << 16);
}
__device__ __forceinline__ ushort_t f2bf(float f) {
  unsigned int u = __float_as_uint(f);
  return (ushort_t)((u + 0x7FFFu + ((u >> 16) & 1u)) >> 16);  // RNE
}
__device__ __forceinline__ float read_f(const void* p, int fm, size_t i) {
  return fm ? bf2f(((const ushort_t*)p)[i]) : ((const float*)p)[i];
}

// fragment-order offset: tile-major 16-row tiles; within tile kc-chunk(32 k)
// then lane-linear (lane = (m&15)+16*((k>>3)&3), 8 elems each).
__device__ __forceinline__ size_t frag_off(int m, int k, int K) {
  return (size_t)(m >> 4) * 16 * K + ((size_t)(k >> 5) << 9) +
         (((k >> 3) & 3) << 7) + ((m & 15) << 3) + (k & 7);
}

// ---------------- prep: sniff (0-2) + W/bias convert (3-34) + zero (35+) ---
__global__ void prep_kernel(const void* __restrict__ x,
                            const void* __restrict__ m1,
                            const void* __restrict__ m2,
                            int* __restrict__ modes,
                            int* __restrict__ zero_region, int zn,
                            const void* __restrict__ W1, const void* __restrict__ W2,
                            const void* __restrict__ W3,
                            const void* __restrict__ b1, const void* __restrict__ b2,
                            const void* __restrict__ b3,
                            ushort_t* __restrict__ whi, ushort_t* __restrict__ wlo,
                            float* __restrict__ biasf,
                            int n1, int n2, int n3, int h1, int h2, int h3,
                            int K1, int K2, int K3) {
  if (blockIdx.x == 0) {
    __shared__ int bfok;
    if (threadIdx.x == 0) bfok = 1;
    __syncthreads();
    for (int i = threadIdx.x; i < 8192; i += blockDim.x) {
      ushort_t h = ((const ushort_t*)x)[i];
      int e = (h >> 7) & 0xFF;
      if (!(h == 0 || (e >= 95 && e <= 133))) atomicAnd(&bfok, 0);
    }
    __syncthreads();
    if (threadIdx.x == 0) modes[0] = bfok;   // 1=bf16, 0=f32
  } else if (blockIdx.x <= 2) {
    const void* p = (blockIdx.x == 1) ? m1 : m2;
    __shared__ int ok[4];  // [i32, f32, bf16, u8]
    if (threadIdx.x < 4) ok[threadIdx.x] = 1;
    __syncthreads();
    for (int i = threadIdx.x; i < 4096; i += blockDim.x) {
      unsigned int w = ((const unsigned int*)p)[i];
      if (!(w == 0u || w == 1u)) atomicAnd(&ok[0], 0);
      if (!(w == 0u || w == 0x3F800000u)) atomicAnd(&ok[1], 0);
      unsigned int h16 = w >> 16, l16 = w & 0xFFFFu;
      if (!((h16 == 0u || h16 == 0x3F80u) && (l16 == 0u || l16 == 0x3F80u)))
        atomicAnd(&ok[2], 0);
      if (((w | (w >> 8) | (w >> 16) | (w >> 24)) & 0xFEu) != 0u) atomicAnd(&ok[3], 0);
    }
    __syncthreads();
    if (threadIdx.x == 0)
      modes[blockIdx.x] = ok[0] ? 1 : (ok[1] ? 2 : (ok[2] ? 3 : 0));
  } else if (blockIdx.x < 35) {
    // W split + bias convert; self-sniff x dtype (weights share x's dtype)
    __shared__ int bfok;
    if (threadIdx.x == 0) bfok = 1;
    __syncthreads();
    for (int i = threadIdx.x; i < 8192; i += blockDim.x) {
      ushort_t h = ((const ushort_t*)x)[i];
      int e = (h >> 7) & 0xFF;
      if (!(h == 0 || (e >= 95 && e <= 133))) atomicAnd(&bfok, 0);
    }
    __syncthreads();
    int fm = bfok;
    int wtot = n1 + n2 + n3;
    int total = wtot + h1 + h2 + h3;
    for (int i = (blockIdx.x - 3) * 256 + threadIdx.x; i < total; i += 32 * 256) {
      if (i < wtot) {
        const void* src; int j, K; size_t base;
        if (i < n1) { src = W1; j = i; K = K1; base = 0; }
        else if (i < n1 + n2) { src = W2; j = i - n1; K = K2; base = n1; }
        else { src = W3; j = i - n1 - n2; K = K3; base = (size_t)n1 + n2; }
        int n = j / K, k = j - n * K;
        float v = read_f(src, fm, j);
        ushort_t h = f2bf(v);
        size_t o = base + frag_off(n, k, K);
        whi[o] = h;
        wlo[o] = f2bf(v - bf2f(h));
      } else {
        int k = i - wtot;
        const void* src; int j;
        if (k < h1) { src = b1; j = k; }
        else if (k < h1 + h2) { src = b2; j = k - h1; }
        else { src = b3; j = k - h1 - h2; }
        biasf[k] = read_f(src, fm, j);
      }
    }
  } else {
    int i = (blockIdx.x - 35) * blockDim.x + threadIdx.x;
    int stride = (gridDim.x - 35) * blockDim.x;
    for (; i < zn; i += stride) zero_region[i] = 0;
  }
}

// ---------------- scans: shard-summing front end ----------------
__global__ void scan_part_kernel(const int* __restrict__ cnt8,
                                 int* __restrict__ cnt,
                                 int* __restrict__ part, int n) {
  __shared__ int s[256];
  int i = blockIdx.x * 256 + threadIdx.x;
  int v = 0;
  if (i < n) {
#pragma unroll
    for (int x = 0; x < 8; ++x) v += cnt8[(size_t)x * n + i];
    cnt[i] = v;
  }
  s[threadIdx.x] = v;
  __syncthreads();
  for (int off = 128; off > 0; off >>= 1) {
    if (threadIdx.x < off) s[threadIdx.x] += s[threadIdx.x + off];
    __syncthreads();
  }
  if (threadIdx.x == 0) part[blockIdx.x] = s[0];
}

__global__ __launch_bounds__(1024) void scan_top_kernel(int* __restrict__ part, int P) {
  __shared__ int s[1024];
  int t = threadIdx.x;
  int v = (t < P) ? part[t] : 0;
  s[t] = v;
  __syncthreads();
  for (int off = 1; off < 1024; off <<= 1) {
    int x = s[t];
    int y = (t >= off) ? s[t - off] : 0;
    __syncthreads();
    s[t] = x + y;
    __syncthreads();
  }
  if (t < P) part[t] = s[t] - v;   // exclusive
}

__global__ void scan_apply_kernel(const int* __restrict__ cnt, const int* __restrict__ part,
                                  int* __restrict__ row_start, int n) {
  __shared__ int s[256];
  int base = part[blockIdx.x];
  int i = blockIdx.x * 256 + threadIdx.x;
  int v = (i < n) ? cnt[i] : 0;
  s[threadIdx.x] = v;
  __syncthreads();
  for (int off = 1; off < 256; off <<= 1) {
    int x = s[threadIdx.x];
    int y = (threadIdx.x >= off) ? s[threadIdx.x - off] : 0;
    __syncthreads();
    s[threadIdx.x] = x + y;
    __syncthreads();
  }
  if (i < n) row_start[i] = base + s[threadIdx.x] - v;
  if (i == n - 1) row_start[n] = base + s[threadIdx.x];
}

// ---------------- pass 1: hist + tile-binning fused (blocks 0..511) --------
// CSR histogram is XCD-sharded: cnt8[(blockIdx&7)*N + r] -> all RMW for a
// given counter line happen within one XCD's L2 (no cross-XCD bouncing).
__global__ void hist_bin_kernel(
    const int* __restrict__ rows, const int* __restrict__ cols,
    const void* __restrict__ vals, const int* __restrict__ fm_p,
    int* __restrict__ cnt8, int* __restrict__ binfill,
    int2* __restrict__ bins, int cap, int use_bins, int2* __restrict__ ovf,
    int E, int Nrows, const void* __restrict__ x, ushort_t* __restrict__ xbf,
    int K1, int nx) {
  int fm = *fm_p;
  const int BIN_BLOCKS = 512;
  if (blockIdx.x < BIN_BLOCKS) {
    int xcd = blockIdx.x & 7;
    int* cnt_s = cnt8 + (size_t)xcd * Nrows;
    if (use_bins) {
      __shared__ int hist[8];
      __shared__ int gbase[8];
      int tid = threadIdx.x;
      for (int tb = blockIdx.x; tb * 1024 < E; tb += BIN_BLOCKS) {
        int base = tb * 1024;
        if (tid < 8) hist[tid] = 0;
        __syncthreads();
        int rr[4], cc[4], pp[4], rk[4]; float vv[4];
#pragma unroll
        for (int j = 0; j < 4; ++j) {
          int i = base + j * 256 + tid;
          if (i < E) {
            rr[j] = rows[i]; cc[j] = cols[i]; vv[j] = read_f(vals, fm, i);
            atomicAdd(&cnt_s[rr[j]], 1);           // XCD-local CSR histogram
            pp[j] = rr[j] >> 13;                   // partition 0..7
            rk[j] = atomicAdd(&hist[pp[j]], 1);    // LDS rank
          } else {
            pp[j] = -1;
          }
        }
        __syncthreads();
        if (tid < 8)
          gbase[tid] = atomicAdd(&binfill[(xcd << 4) + tid], hist[tid]);
        __syncthreads();
#pragma unroll
        for (int j = 0; j < 4; ++j) {
          if (pp[j] >= 0) {
            int pos = gbase[pp[j]] + rk[j];
            if (pos < cap) {
              bins[(size_t)((xcd << 3) + pp[j]) * cap + pos] =
                  make_int2((rr[j] << 16) | cc[j], __float_as_int(vv[j]));
            } else {  // overflow (skewed rows): append to ovf list
              int op = atomicAdd(&binfill[128], 1);
              ovf[op] = make_int2((rr[j] << 16) | cc[j], __float_as_int(vv[j]));
            }
          }
        }
      }
    } else {
      // fallback (N > 65535): hist only; pass 2 does the direct scatter
      int i = blockIdx.x * blockDim.x + threadIdx.x;
      int stride = BIN_BLOCKS * blockDim.x;
      for (; i < E; i += stride) atomicAdd(&cnt_s[rows[i]], 1);
    }
  } else {
    // x -> bf16 frag conversion (only when x is f32)
    if (fm == 1) return;
    int nx4 = nx / 4;
    int i = (blockIdx.x - BIN_BLOCKS) * blockDim.x + threadIdx.x;
    int stride = (gridDim.x - BIN_BLOCKS) * blockDim.x;
    for (; i < nx4; i += stride) {
      int m = i / (K1 / 4);
      int k0 = (i - m * (K1 / 4)) * 4;
      f32x4 v = ((const f32x4*)x)[i];
      ushort_t p0 = f2bf(v[0]), p1 = f2bf(v[1]), p2 = f2bf(v[2]), p3 = f2bf(v[3]);
      size_t o = frag_off(m, k0, K1);
      *(u32x2*)(xbf + o) = (u32x2){
          (unsigned int)p0 | ((unsigned int)p1 << 16),
          (unsigned int)p2 | ((unsigned int)p3 << 16)};
    }
  }
}

// ---------------- GEMM body (frozen r15 core, device-callable) --------------
template<int KC>
__device__ __forceinline__ void load_afrag(const ushort_t* __restrict__ A,
                                           const ushort_t* __restrict__ Xrow,
                                           bool rowA, int mtile, int K,
                                           int lane, int mr, int quad, int M,
                                           bf16x8* dst) {
  if (rowA) {
    int rr = mtile * 16 + mr;
    if (rr >= M) rr = M - 1;
    const ushort_t* ap = Xrow + (size_t)rr * K + quad * 8;
#pragma unroll
    for (int kc = 0; kc < KC; ++kc) dst[kc] = *(const bf16x8*)(ap + kc * 32);
  } else {
    const ushort_t* ap = A + (size_t)mtile * 16 * K + lane * 8;
#pragma unroll
    for (int kc = 0; kc < KC; ++kc) dst[kc] = *(const bf16x8*)(ap + kc * 512);
  }
}

template<int KC>
__device__ __forceinline__ void gemm_dev(
    int vbid, int nblk, int tid,
    const ushort_t* __restrict__ A, const ushort_t* __restrict__ Xrow, int fm,
    const ushort_t* __restrict__ Whi, const ushort_t* __restrict__ Wlo,
    const float* __restrict__ bias, ushort_t* __restrict__ g, int ldg,
    int M, int nct) {
  const int K = KC * 32;
  int wave = tid >> 6, lane = tid & 63;
  int gw = vbid * 4 + wave;
  int NW = nblk * 4;
  int mr = lane & 15, quad = lane >> 4;
  int ct = gw % nct;
  int nrt = (M + 15) >> 4;
  int ntasks = nct * nrt;
  if (gw >= ntasks) return;

  bool rowA = (Xrow != nullptr) && (fm != 0);

  bf16x8 wh[KC], wl[KC];
  {
    const ushort_t* wp = Whi + (size_t)ct * 16 * K + lane * 8;
    const ushort_t* wq = Wlo + (size_t)ct * 16 * K + lane * 8;
#pragma unroll
    for (int kc = 0; kc < KC; ++kc) {
      wh[kc] = *(const bf16x8*)(wp + kc * 512);
      wl[kc] = *(const bf16x8*)(wq + kc * 512);
    }
  }
  int col = ct * 16 + mr;
  float bv = bias[col];

  int task = gw;
  bf16x8 af[KC];
  load_afrag<KC>(A, Xrow, rowA, task / nct, K, lane, mr, quad, M, af);

#pragma unroll 1
  for (;;) {
    int next = task + NW;
    bool has_next = next < ntasks;
    bf16x8 afn[KC];
    if (has_next)
      load_afrag<KC>(A, Xrow, rowA, next / nct, K, lane, mr, quad, M, afn);

    f32x4 acc[4];
#pragma unroll
    for (int t = 0; t < 4; ++t) acc[t] = (f32x4){0.f, 0.f, 0.f, 0.f};
#pragma unroll
    for (int kc = 0; kc < KC; ++kc) {
      acc[(2 * kc) & 3] = __builtin_amdgcn_mfma_f32_16x16x32_bf16(af[kc], wh[kc], acc[(2 * kc) & 3], 0, 0, 0);
      acc[(2 * kc + 1) & 3] = __builtin_amdgcn_mfma_f32_16x16x32_bf16(af[kc], wl[kc], acc[(2 * kc + 1) & 3], 0, 0, 0);
    }
    int m0 = (task / nct) * 16;
#pragma unroll
    for (int r = 0; r < 4; ++r) {
      int row = m0 + quad * 4 + r;
      float s = ((acc[0][r] + acc[1][r]) + (acc[2][r] + acc[3][r])) + bv;
      if (row < M) g[(size_t)row * ldg + col] = f2bf(s);
    }
    if (!has_next) break;
#pragma unroll
    for (int kc = 0; kc < KC; ++kc) af[kc] = afn[kc];
    task = next;
  }
}

template<int KC>
__global__ __launch_bounds__(256) void gemm_breg_kernel(
    const ushort_t* __restrict__ A,
    const ushort_t* __restrict__ Xrow, const int* __restrict__ fm_p,
    const ushort_t* __restrict__ Whi, const ushort_t* __restrict__ Wlo,
    const float* __restrict__ bias, ushort_t* __restrict__ g, int ldg,
    int M, int nct) {
  gemm_dev<KC>(blockIdx.x, gridDim.x, threadIdx.x, A, Xrow, *fm_p,
               Whi, Wlo, bias, g, ldg, M, nct);
}

// ---------------- pass 2 + GEMM-1 fused -------------------------------------
__global__ __launch_bounds__(256) void scatter_gemm_kernel(
    const int2* __restrict__ bins, const int* __restrict__ binfill,
    const int* __restrict__ row_start, int* __restrict__ fill,
    int2* __restrict__ ecv, int cap, const int2* __restrict__ ovf,
    const int* __restrict__ rows, const int* __restrict__ cols,
    const void* __restrict__ vals, const int* __restrict__ fm_p,
    int use_bins, int E,
    const ushort_t* __restrict__ A, const ushort_t* __restrict__ Xrow,
    const ushort_t* __restrict__ Whi, const ushort_t* __restrict__ Wlo,
    const float* __restrict__ bias, ushort_t* __restrict__ g, int ldg,
    int M, int nct) {
  if (blockIdx.x >= 1024) {
    gemm_dev<8>(blockIdx.x - 1024, 1024, threadIdx.x, A, Xrow, *fm_p,
                Whi, Wlo, bias, g, ldg, M, nct);
    return;
  }
  if (use_bins) {
    int p = blockIdx.x & 7, q = blockIdx.x >> 3;
#pragma unroll 1
    for (int x = 0; x < 8; ++x) {
      int n = binfill[x * 16 + p];
      if (n > cap) n = cap;
      const int2* bp = bins + (size_t)((x << 3) + p) * cap;
      for (int e = q * 256 + (int)threadIdx.x; e < n; e += 128 * 256) {
        int2 ent = bp[e];
        int r = ((unsigned int)ent.x) >> 16;
        int c = ent.x & 0xFFFF;
        int pos = atomicAdd(&fill[r], 1);
        ecv[row_start[r] + pos] = make_int2(c, ent.y);
      }
    }
    int ovfn = binfill[128];
    for (int e = blockIdx.x * 256 + (int)threadIdx.x; e < ovfn; e += 1024 * 256) {
      int2 ent = ovf[e];
      int r = ((unsigned int)ent.x) >> 16;
      int c = ent.x & 0xFFFF;
      int pos = atomicAdd(&fill[r], 1);
      ecv[row_start[r] + pos] = make_int2(c, ent.y);
    }
  } else {
    int fm = *fm_p;
    for (int i = blockIdx.x * 256 + (int)threadIdx.x; i < E; i += 1024 * 256) {
      int r = rows[i];
      int pos = atomicAdd(&fill[r], 1);
      ecv[row_start[r] + pos] = make_int2(cols[i], __float_as_int(read_f(vals, fm, i)));
    }
  }
}

// ---------------- SpMM v9: deep-MLP gathers (frozen r21) --------------------
template<int VEC, int CHUNK, bool CLAMP>
__device__ __forceinline__ void spmm_chunk(const int2* __restrict__ ecv,
                                           int base, int e1,
                                           const ushort_t* __restrict__ G,
                                           int D, int f0, float* a) {
  int2 cv[CHUNK];
#pragma unroll
  for (int j = 0; j < CHUNK; ++j) {
    int ee = base + j;
    if (CLAMP) ee = (ee < e1) ? ee : e1 - 1;
    cv[j] = ecv[ee];
  }
  float v[CHUNK];
#pragma unroll
  for (int j = 0; j < CHUNK; ++j) {
    v[j] = __int_as_float(cv[j].y);
    if (CLAMP && (base + j >= e1)) v[j] = 0.f;
  }
  if (VEC == 4) {
    u32x2 gg[CHUNK];
#pragma unroll
    for (int j = 0; j < CHUNK; ++j)
      gg[j] = *(const u32x2*)(G + (size_t)cv[j].x * D + f0);
#pragma unroll
    for (int j = 0; j < CHUNK; ++j) {
      a[0] += v[j] * bf2f((ushort_t)gg[j][0]);
      a[1] += v[j] * bf2f((ushort_t)(gg[j][0] >> 16));
      a[2] += v[j] * bf2f((ushort_t)gg[j][1]);
      a[3] += v[j] * bf2f((ushort_t)(gg[j][1] >> 16));
    }
  } else if (VEC == 2) {
    unsigned int gg[CHUNK];
#pragma unroll
    for (int j = 0; j < CHUNK; ++j)
      gg[j] = *(const unsigned int*)(G + (size_t)cv[j].x * D + f0);
#pragma unroll
    for (int j = 0; j < CHUNK; ++j) {
      a[0] += v[j] * bf2f((ushort_t)gg[j]);
      a[1] += v[j] * bf2f((ushort_t)(gg[j] >> 16));
    }
  } else {
    ushort_t h[CHUNK];
#pragma unroll
    for (int j = 0; j < CHUNK; ++j) h[j] = G[(size_t)cv[j].x * D + f0];
#pragma unroll
    for (int j = 0; j < CHUNK; ++j) a[0] += v[j] * bf2f(h[j]);
  }
}

template<int MODE, int VEC>
__global__ __launch_bounds__(256) void spmm8_kernel(
    const int* __restrict__ row_start, const int2* __restrict__ ecv,
    const ushort_t* __restrict__ G, int D,
    const void* __restrict__ mask, const int* __restrict__ mmode_p,
    void* __restrict__ outp, int N) {
  __shared__ ushort_t stage[1024];         // 4 rows x up to 256 cols
  int wave = threadIdx.x >> 6, lane = threadIdx.x & 63;
  int r = blockIdx.x * 4 + wave;
  bool active = r < N;
  float a[VEC];
#pragma unroll
  for (int q = 0; q < VEC; ++q) a[q] = 0.f;
  int f0 = lane * VEC;

  // ---- hoisted mask load (independent of gather chain) ----
  bool keep[VEC];
#pragma unroll
  for (int q = 0; q < VEC; ++q) keep[q] = true;
  if (MODE == 1 && active) {
    size_t om = (size_t)r * D + f0;        // mask is row-major
    int mm = *mmode_p;
    if (mm == 1 || mm == 2) {              // 4B/elem: vector load
      if (VEC == 4) {
        u32x4 mv = *(const u32x4*)((const unsigned int*)mask + om);
#pragma unroll
        for (int q = 0; q < VEC; ++q) keep[q] = mv[q] != 0u;
      } else if (VEC == 2) {
        u32x2 mv = *(const u32x2*)((const unsigned int*)mask + om);
#pragma unroll
        for (int q = 0; q < VEC; ++q) keep[q] = mv[q] != 0u;
      } else {
        keep[0] = ((const unsigned int*)mask)[om] != 0u;
      }
    } else if (mm == 3) {                  // bf16: vector load
      if (VEC == 4) {
        u32x2 mv = *(const u32x2*)((const ushort_t*)mask + om);
        keep[0] = (mv[0] & 0xFFFFu) != 0u; keep[1] = (mv[0] >> 16) != 0u;
        keep[2] = (mv[1] & 0xFFFFu) != 0u; keep[3] = (mv[1] >> 16) != 0u;
      } else if (VEC == 2) {
        unsigned int mv = *(const unsigned int*)((const ushort_t*)mask + om);
        keep[0] = (mv & 0xFFFFu) != 0u; keep[1] = (mv >> 16) != 0u;
      } else {
        keep[0] = ((const ushort_t*)mask)[om] != 0;
      }
    } else {                               // u8: vector load
      if (VEC == 4) {
        unsigned int mv = *(const unsigned int*)((const unsigned char*)mask + om);
        keep[0] = (mv & 0xFFu) != 0u;         keep[1] = ((mv >> 8) & 0xFFu) != 0u;
        keep[2] = ((mv >> 16) & 0xFFu) != 0u; keep[3] = (mv >> 24) != 0u;
      } else if (VEC == 2) {
        unsigned int mv = *(const unsigned short*)((const unsigned char*)mask + om);
        keep[0] = (mv & 0xFFu) != 0u; keep[1] = ((mv >> 8) & 0xFFu) != 0u;
      } else {
        keep[0] = ((const unsigned char*)mask)[om] != 0;
      }
    }
  }

  if (active) {
    int e  = __builtin_amdgcn_readfirstlane(row_start[r]);
    int e1 = __builtin_amdgcn_readfirstlane(row_start[r + 1]);
    for (; e + 16 <= e1; e += 16)
      spmm_chunk<VEC, 16, false>(ecv, e, e1, G, D, f0, a);
    for (; e < e1; e += 8)
      spmm_chunk<VEC, 8, true>(ecv, e, e1, G, D, f0, a);
  }

  if (MODE == 1) {
    if (active) {
#pragma unroll
      for (int q = 0; q < VEC; ++q) {
        float t = a[q];
        t = (t >= 0.f) ? t : 0.2f * t;             // leaky relu 0.2
        t = keep[q] ? t * 1.25f : 0.f;             // keep = 1/(1-0.2)
        stage[wave * D + f0 + q] = f2bf(t);
      }
    }
    __syncthreads();
    // flush: D threads, one 8B (4-elem) piece each; 64B line = 4 rows' chunks
    if (threadIdx.x < D) {
      int g = threadIdx.x >> 3, s = threadIdx.x & 7;   // group, sub
      int kc = g >> 2, quad = g & 3;
      int sr = s >> 1;                                  // source row in block
      int r0 = blockIdx.x * 4;
      if (r0 + sr < N) {
        int kk = kc * 32 + quad * 8 + (s & 1) * 4;
        size_t dst = (size_t)(r0 >> 4) * 16 * D + ((size_t)kc << 9) +
                     (quad << 7) + ((r0 & 15) << 3) + s * 4;
        *(u32x2*)((ushort_t*)outp + dst) = *(const u32x2*)(stage + sr * D + kk);
      }
    }
  } else {
    if (active) {
      size_t o = (size_t)r * D + f0;
#pragma unroll
      for (int q = 0; q < VEC; ++q) ((float*)outp)[o + q] = a[q];
    }
  }
}

// ---------------- launch ----------------
extern "C" void kernel_launch(void* const* d_in, const int* in_sizes, int n_in,
                              void* d_out, int out_size, void* d_ws, size_t ws_size,
                              hipStream_t stream) {
  const void* x     = d_in[0];
  const int*  rows  = (const int*)d_in[1];
  const int*  cols  = (const int*)d_in[2];
  const void* vals  = d_in[3];
  const void* W1    = d_in[4];
  const void* b1    = d_in[5];
  const void* W2    = d_in[6];
  const void* b2    = d_in[7];
  const void* W3    = d_in[8];
  const void* b3    = d_in[9];
  const void* mask1 = d_in[10];
  const void* mask2 = d_in[11];

  const int H1  = in_sizes[5];            // 256
  const int H2  = in_sizes[7];            // 128
  const int OUT = in_sizes[9];            // 64
  const int IN  = in_sizes[4] / H1;       // 256
  const int N   = in_sizes[0] / IN;       // 50000
  const int E   = in_sizes[1];            // 800000
  const int W1n = in_sizes[4], W2n = in_sizes[6], W3n = in_sizes[8];
  const int Np  = ((N + 15) / 16) * 16;
  const int CAP = (E >> 5) + 2048;        // per-bin cap (avg E/64, 2x+ slack)
  const int use_bins = (N <= 65535) ? 1 : 0;

  char* ws = (char*)d_ws;
  size_t off = 0;
  auto alloc = [&](size_t bytes) -> void* {
    void* p = ws + off;
    off = (off + bytes + 255) & ~(size_t)255;
    return p;
  };
  int*      modes     = (int*)alloc(4 * 4);
  int*      row_start = (int*)alloc((size_t)(N + 1) * 4);
  // meta: [cnt8(8N) | cnt(N) | fill(N) | binfill(132)] -- zero whole region
  int*      meta      = (int*)alloc(((size_t)10 * N + 192) * 4);
  int*      part      = (int*)alloc(1024 * 4);
  int2*     ecv       = (int2*)alloc((size_t)E * 8);
  int2*     bins      = (int2*)alloc((size_t)64 * CAP * 8);
  int2*     ovf       = (int2*)alloc((size_t)E * 8);
  ushort_t* whi       = (ushort_t*)alloc((size_t)(W1n + W2n + W3n) * 2);
  ushort_t* wlo       = (ushort_t*)alloc((size_t)(W1n + W2n + W3n) * 2);
  float*    biasf     = (float*)alloc((size_t)(H1 + H2 + OUT) * 4);
  ushort_t* bufA      = (ushort_t*)alloc((size_t)Np * H1 * 2);   // frag
  ushort_t* bufB      = (ushort_t*)alloc((size_t)Np * H1 * 2);   // row-major G
  ushort_t* bufC      = (ushort_t*)alloc((size_t)Np * H1 * 2);   // frag
  // total ~107 MB (<=110 MB proven safe in r3)

  int* fmode   = modes;
  int* mm1     = modes + 1;
  int* mm2     = modes + 2;
  int* cnt8    = meta;                     // 8N, XCD-sharded histogram
  int* cnt     = meta + 8 * N;             // N, shard sum (written by scan)
  int* fill    = meta + 9 * N;             // N
  int* binfill = meta + 10 * N;            // 128 bin ctrs + ovf ctr [128]
  ushort_t* w1hi = whi,             *w1lo = wlo;
  ushort_t* w2hi = whi + W1n,       *w2lo = wlo + W1n;
  ushort_t* w3hi = whi + W1n + W2n, *w3lo = wlo + W1n + W2n;

  // 1. prep: sniff + W/bias convert (self-sniff) + zero meta region
  prep_kernel<<<512, 256, 0, stream>>>(
      x, mask1, mask2, modes, meta, 10 * N + 192,
      W1, W2, W3, b1, b2, b3, whi, wlo, biasf,
      W1n, W2n, W3n, H1, H2, OUT, IN, H1, H2);

  // 2. hist(sharded) + binning fused (512 blocks) + x-frag convert f32
  hist_bin_kernel<<<1536, 256, 0, stream>>>(
      rows, cols, vals, fmode, cnt8, binfill, bins, CAP, use_bins, ovf,
      E, N, x, bufA, IN, N * IN);

  // 3-5. CSR scans (front end sums the 8 shards)
  const int P = (N + 255) / 256;
  scan_part_kernel<<<P, 256, 0, stream>>>(cnt8, cnt, part, N);
  scan_top_kernel<<<1, 1024, 0, stream>>>(part, P);
  scan_apply_kernel<<<P, 256, 0, stream>>>(cnt, part, row_start, N);

  // 6. pass 2 (bin->ecv scatter, 1024 blocks) || GEMM-1 (1024 blocks)
  scatter_gemm_kernel<<<2048, 256, 0, stream>>>(
      bins, binfill, row_start, fill, ecv, CAP, ovf,
      rows, cols, vals, fmode, use_bins, E,
      bufA, (const ushort_t*)x, w1hi, w1lo, biasf, bufB, H1, N, H1 / 16);

  int spmm_grid = (N + 3) / 4;
  const int GEMM_BLOCKS = 1024;

  // 7-11. SpMM/GEMM chain
  spmm8_kernel<1, 4><<<spmm_grid, 256, 0, stream>>>(
      row_start, ecv, bufB, H1, mask1, mm1, bufC, N);
  gemm_breg_kernel<8><<<GEMM_BLOCKS, 256, 0, stream>>>(
      bufC, nullptr, fmode, w2hi, w2lo, biasf + H1, bufB, H2, N, H2 / 16);
  spmm8_kernel<1, 2><<<spmm_grid, 256, 0, stream>>>(
      row_start, ecv, bufB, H2, mask2, mm2, bufA, N);
  gemm_breg_kernel<4><<<GEMM_BLOCKS, 256, 0, stream>>>(
      bufA, nullptr, fmode, w3hi, w3lo, biasf + H1 + H2, bufB, OUT, N, OUT / 16);
  spmm8_kernel<0, 1><<<spmm_grid, 256, 0, stream>>>(
      row_start, ecv, bufB, OUT, nullptr, fmode, d_out, N);
}